// Round 3
// baseline (1180.084 us; speedup 1.0000x reference)
//
#include <hip/hip_runtime.h>

#define NHALF 32
#define NDIM  64
#define NHID  256
#define NPAR  736   // (3K-1)*HALF = 23*32

typedef unsigned short u16;
typedef unsigned int   u32;

__device__ __forceinline__ float bf2f(u16 h){ return __uint_as_float(((u32)h) << 16); }
__device__ __forceinline__ u16 f2bf(float f){
  u32 u = __float_as_uint(f);
  u += 0x7FFFu + ((u >> 16) & 1u);   // round-to-nearest-even
  return (u16)(u >> 16);
}
__device__ __forceinline__ float tanh_fast(float x){
  x = fminf(15.f, fmaxf(-15.f, x));
  float e = __expf(2.f * x);
  return (e - 1.f) / (e + 1.f);
}
__device__ __forceinline__ float softplus_f(float x){
  return fmaxf(x, 0.f) + log1pf(__expf(-fabsf(x)));
}

// C[N x J] (bf16) = act(A[:, acol0 : acol0+K] @ W[K x J] + b)
// A: fp32 (ABF16=false) with row stride lda, or bf16 (ABF16=true).
template<bool ABF16, bool TANH>
__global__ __launch_bounds__(256)
void gemm_k(const void* __restrict__ Av, int lda, int acol0,
            const float* __restrict__ W, const float* __restrict__ bias,
            u16* __restrict__ C, int K, int J)
{
  // As: transposed A-tile [k][row], row-pad to 132 words (16B-aligned k-rows,
  // conflict-free b128 reads: bank = (4k + 8ty + w) % 32 covers all 32 banks).
  __shared__ float  As[32 * 132];
  __shared__ float4 Ws4[32 * 32];   // [k][col4], thread reads col4 = tx and 16+tx (2-way = free)
  const int t  = threadIdx.x;
  const int tx = t & 15, ty = t >> 4;
  const int row0 = blockIdx.x * 128;
  const int jb   = blockIdx.y * 128;

  float acc[8][8];
  #pragma unroll
  for (int i = 0; i < 8; i++)
    #pragma unroll
    for (int j = 0; j < 8; j++) acc[i][j] = 0.f;

  for (int kk = 0; kk < K; kk += 32){
    if constexpr (ABF16){
      const u16* A = (const u16*)Av;
      #pragma unroll
      for (int i = 0; i < 2; i++){
        int idx = t + i * 256;            // 512 loads of 8 bf16
        int r = idx >> 2, c = (idx & 3) * 8;
        uint4 v = *(const uint4*)(A + (size_t)(row0 + r) * lda + acol0 + kk + c);
        u16 us[8]; *(uint4*)us = v;
        #pragma unroll
        for (int j = 0; j < 8; j++) As[(c + j) * 132 + r] = bf2f(us[j]);
      }
    } else {
      const float* A = (const float*)Av;
      #pragma unroll
      for (int i = 0; i < 4; i++){
        int idx = t + i * 256;            // 1024 float4 loads
        int r = idx >> 3, c = (idx & 7) * 4;
        float4 v = *(const float4*)(A + (size_t)(row0 + r) * lda + acol0 + kk + c);
        As[(c + 0) * 132 + r] = v.x; As[(c + 1) * 132 + r] = v.y;
        As[(c + 2) * 132 + r] = v.z; As[(c + 3) * 132 + r] = v.w;
      }
    }
    #pragma unroll
    for (int i = 0; i < 4; i++){
      int idx = t + i * 256;
      int r = idx >> 5, c4 = idx & 31;
      int col = jb + c4 * 4;
      float4 v = make_float4(0.f, 0.f, 0.f, 0.f);
      if (col + 3 < J) v = *(const float4*)(W + (size_t)(kk + r) * J + col);
      Ws4[r * 32 + c4] = v;
    }
    __syncthreads();

    const float4* As4 = (const float4*)As;
    #pragma unroll 4
    for (int k = 0; k < 32; k++){
      float4 a0 = As4[k * 33 + ty * 2];
      float4 a1 = As4[k * 33 + ty * 2 + 1];
      float4 b0 = Ws4[k * 32 + tx];
      float4 b1 = Ws4[k * 32 + 16 + tx];
      float aa[8] = {a0.x, a0.y, a0.z, a0.w, a1.x, a1.y, a1.z, a1.w};
      float bb[8] = {b0.x, b0.y, b0.z, b0.w, b1.x, b1.y, b1.z, b1.w};
      #pragma unroll
      for (int i = 0; i < 8; i++)
        #pragma unroll
        for (int j = 0; j < 8; j++) acc[i][j] += aa[i] * bb[j];
    }
    __syncthreads();
  }

  #pragma unroll
  for (int i = 0; i < 8; i++){
    int row = row0 + ty * 8 + i;
    #pragma unroll
    for (int j = 0; j < 8; j++){
      int col = jb + (j < 4 ? tx * 4 + j : 64 + tx * 4 + (j - 4));
      if (col < J){
        float v = acc[i][j] + bias[col];
        if constexpr (TANH) v = tanh_fast(v);
        C[(size_t)row * J + col] = f2bf(v);
      }
    }
  }
}

// Per (sample, dim) rational-quadratic spline. 8 samples/block, 256 threads.
// PHASE 0: transform upper (xcol=32), write ld partial.
// PHASE 1: transform lower (xcol=0), write final logdet = ldp + sum.
template<int PHASE>
__global__ __launch_bounds__(256)
void spline_k(const float* __restrict__ x,       // N x 64 original input
              const u16* __restrict__ params,    // N x 736 bf16
              float* __restrict__ out,           // N x 64 (d_out)
              float* __restrict__ ldp,           // ws partial logdet (N)
              float* __restrict__ ldout,         // d_out + N*64
              int xcol)
{
  __shared__ u16 pb[8 * NPAR];                   // 11776 B = 736 uint4
  const int t = threadIdx.x;
  const int s0 = blockIdx.x * 8;

  { // stage 8 rows of params: 5888 bf16 = 736 uint4 (8 bf16 per uint4)
    const uint4* src = (const uint4*)(params + (size_t)s0 * NPAR);
    uint4* dst = (uint4*)pb;
    dst[t]       = src[t];
    dst[256 + t] = src[256 + t];
    if (t < 224) dst[512 + t] = src[512 + t];
  }
  __syncthreads();

  const int si = t >> 5, d = t & 31;
  const int s = s0 + si;
  const u16* pp = pb + si * NPAR + d * 23;
  float p[23];
  #pragma unroll
  for (int e = 0; e < 23; e++) p[e] = bf2f(pp[e]);

  // ---- _coupling_params: W = 6*softmax(raw), H = 6*softmax(raw), D = softplus(raw)
  float W6[8], H6[8];
  {
    float m = p[0];
    #pragma unroll
    for (int i = 1; i < 8; i++) m = fmaxf(m, p[i]);
    float sm = 0.f;
    #pragma unroll
    for (int i = 0; i < 8; i++){ W6[i] = __expf(p[i] - m); sm += W6[i]; }
    float r = 6.f / sm;
    #pragma unroll
    for (int i = 0; i < 8; i++) W6[i] *= r;
  }
  {
    float m = p[8];
    #pragma unroll
    for (int i = 1; i < 8; i++) m = fmaxf(m, p[8 + i]);
    float sm = 0.f;
    #pragma unroll
    for (int i = 0; i < 8; i++){ H6[i] = __expf(p[8 + i] - m); sm += H6[i]; }
    float r = 6.f / sm;
    #pragma unroll
    for (int i = 0; i < 8; i++) H6[i] *= r;
  }

  // ---- rqs: widths = 0.001 + 0.992*softmax(W6); cum to [-3,3]
  float wd[8], cumw[9];
  {
    float m = W6[0];
    #pragma unroll
    for (int i = 1; i < 8; i++) m = fmaxf(m, W6[i]);
    float sm = 0.f;
    #pragma unroll
    for (int i = 0; i < 8; i++){ wd[i] = __expf(W6[i] - m); sm += wd[i]; }
    float r = 1.f / sm;
    #pragma unroll
    for (int i = 0; i < 8; i++) wd[i] = 0.001f + 0.992f * wd[i] * r;
  }
  cumw[0] = -3.f;
  { float run = 0.f;
    #pragma unroll
    for (int i = 0; i < 8; i++){ run += wd[i]; cumw[i + 1] = 6.f * run - 3.f; } }
  cumw[8] = 3.f;
  #pragma unroll
  for (int i = 0; i < 8; i++) wd[i] = cumw[i + 1] - cumw[i];

  float hg[8], cumh[9];
  {
    float m = H6[0];
    #pragma unroll
    for (int i = 1; i < 8; i++) m = fmaxf(m, H6[i]);
    float sm = 0.f;
    #pragma unroll
    for (int i = 0; i < 8; i++){ hg[i] = __expf(H6[i] - m); sm += hg[i]; }
    float r = 1.f / sm;
    #pragma unroll
    for (int i = 0; i < 8; i++) hg[i] = 0.001f + 0.992f * hg[i] * r;
  }
  cumh[0] = -3.f;
  { float run = 0.f;
    #pragma unroll
    for (int i = 0; i < 8; i++){ run += hg[i]; cumh[i + 1] = 6.f * run - 3.f; } }
  cumh[8] = 3.f;
  #pragma unroll
  for (int i = 0; i < 8; i++) hg[i] = cumh[i + 1] - cumh[i];

  // derivs[0]=derivs[8]=1 (softplus of pad const); inner: 0.001 + softplus(softplus(raw))
  float dv[9];
  dv[0] = 1.f; dv[8] = 1.f;
  #pragma unroll
  for (int j = 0; j < 7; j++){
    float Dj = softplus_f(p[16 + j]);
    dv[j + 1] = 0.001f + softplus_f(Dj);
  }

  const float xv  = x[(size_t)s * NDIM + xcol + d];
  const float xin = fminf(3.f, fmaxf(-3.f, xv));

  int b = 0;
  #pragma unroll
  for (int j = 1; j < 8; j++) b += (xin >= cumw[j]) ? 1 : 0;

  float in_cw = 0.f, in_w = 0.f, in_ch = 0.f, in_h = 0.f, in_d = 0.f, in_d1 = 0.f;
  #pragma unroll
  for (int j = 0; j < 8; j++){
    if (j == b){ in_cw = cumw[j]; in_w = wd[j]; in_ch = cumh[j];
                 in_h = hg[j];  in_d = dv[j]; in_d1 = dv[j + 1]; }
  }

  float th    = (xin - in_cw) / in_w;
  float tt    = th * (1.f - th);
  float delta = in_h / in_w;
  float numer = in_h * (delta * th * th + in_d * tt);
  float denom = delta + (in_d + in_d1 - 2.f * delta) * tt;
  float outv  = in_ch + numer / denom;
  float omt   = 1.f - th;
  float dnum  = delta * delta * (in_d1 * th * th + 2.f * delta * tt + in_d * omt * omt);
  float lad   = __logf(dnum) - 2.f * __logf(denom);

  bool inside = (xv >= -3.f) && (xv <= 3.f);
  outv = inside ? outv : xv;
  lad  = inside ? lad  : 0.f;

  out[(size_t)s * NDIM + xcol + d] = outv;

  float v = lad;
  #pragma unroll
  for (int mm = 1; mm < 32; mm <<= 1) v += __shfl_xor(v, mm, 64);
  if (d == 0){
    if (PHASE == 0) ldp[s] = v;
    else            ldout[s] = ldp[s] + v;
  }
}

extern "C" void kernel_launch(void* const* d_in, const int* in_sizes, int n_in,
                              void* d_out, int out_size, void* d_ws, size_t ws_size,
                              hipStream_t stream)
{
  const float* x    = (const float*)d_in[0];
  const float* f1w0 = (const float*)d_in[1];
  const float* f1b0 = (const float*)d_in[2];
  const float* f1w1 = (const float*)d_in[3];
  const float* f1b1 = (const float*)d_in[4];
  const float* f1w2 = (const float*)d_in[5];
  const float* f1b2 = (const float*)d_in[6];
  const float* f2w0 = (const float*)d_in[7];
  const float* f2b0 = (const float*)d_in[8];
  const float* f2w1 = (const float*)d_in[9];
  const float* f2b1 = (const float*)d_in[10];
  const float* f2w2 = (const float*)d_in[11];
  const float* f2b2 = (const float*)d_in[12];

  const int N = in_sizes[0] / NDIM;   // 65536
  float* out = (float*)d_out;

  // workspace: h1 (N*256 bf16) | h2 (N*256 bf16) | params (N*736 bf16) | ld1 (N f32)
  u16* h1 = (u16*)d_ws;
  u16* h2 = h1 + (size_t)N * NHID;
  u16* pr = h2 + (size_t)N * NHID;
  float* ld1 = (float*)(pr + (size_t)N * NPAR);

  dim3 blk(256);
  dim3 g1(N / 128, NHID / 128);            // 512 x 2
  dim3 g3(N / 128, (NPAR + 127) / 128);    // 512 x 6
  dim3 gs(N / 8);

  float* ldout = out + (size_t)N * NDIM;

  // ---- coupling 1: MLP f1(lower = x[:, :32]) -> transform upper
  gemm_k<false, true ><<<g1, blk, 0, stream>>>((const void*)x,  NDIM, 0,  f1w0, f1b0, h1, NHALF, NHID);
  gemm_k<true,  true ><<<g1, blk, 0, stream>>>((const void*)h1, NHID, 0,  f1w1, f1b1, h2, NHID,  NHID);
  gemm_k<true,  false><<<g3, blk, 0, stream>>>((const void*)h2, NHID, 0,  f1w2, f1b2, pr, NHID,  NPAR);
  spline_k<0><<<gs, blk, 0, stream>>>(x, pr, out, ld1, ldout, NHALF);

  // ---- coupling 2: MLP f2(new upper = out[:, 32:]) -> transform lower
  gemm_k<false, true ><<<g1, blk, 0, stream>>>((const void*)out, NDIM, NHALF, f2w0, f2b0, h1, NHALF, NHID);
  gemm_k<true,  true ><<<g1, blk, 0, stream>>>((const void*)h1,  NHID, 0,     f2w1, f2b1, h2, NHID,  NHID);
  gemm_k<true,  false><<<g3, blk, 0, stream>>>((const void*)h2,  NHID, 0,     f2w2, f2b2, pr, NHID,  NPAR);
  spline_k<1><<<gs, blk, 0, stream>>>(x, pr, out, ld1, ldout, 0);
}

// Round 4
// 557.976 us; speedup vs baseline: 2.1149x; 2.1149x over previous
//
#include <hip/hip_runtime.h>

#define NHALF 32
#define NDIM  64
#define NHID  256
#define NPAR  736   // (3K-1)*HALF = 23*32

typedef unsigned short u16;
typedef unsigned int   u32;
typedef __attribute__((ext_vector_type(8))) short short8;   // 8 bf16 = 4 VGPR
typedef __attribute__((ext_vector_type(4))) float f32x4;

__device__ __forceinline__ float bf2f(u16 h){ return __uint_as_float(((u32)h) << 16); }
__device__ __forceinline__ u16 f2bf(float f){
  u32 u = __float_as_uint(f);
  u += 0x7FFFu + ((u >> 16) & 1u);   // round-to-nearest-even
  return (u16)(u >> 16);
}
__device__ __forceinline__ float tanh_fast(float x){
  x = fminf(15.f, fmaxf(-15.f, x));
  float e = __expf(2.f * x);
  return (e - 1.f) / (e + 1.f);
}
__device__ __forceinline__ float softplus_f(float x){
  return fmaxf(x, 0.f) + log1pf(__expf(-fabsf(x)));
}

__device__ __forceinline__ void gload16(const u16* g, u16* l){
  __builtin_amdgcn_global_load_lds(
      (const __attribute__((address_space(1))) unsigned int*)(g),
      (__attribute__((address_space(3))) unsigned int*)(l), 16, 0, 0);
}

// ---------------- MFMA GEMM: C[M x Jreal](bf16) = act(A[M x K](bf16) @ Wt^T + bias)
// A dense row-major (lda=K). Wt: bf16 [Jpad][K] (n-major, k-contiguous), rows>=Jreal zeroed.
// 128x128 tile, 4 waves (2x2), per-wave 64x64 = 4x4 frags of 16x16x32.
// LDS fragment-contiguous: subtile = 16(m|n) x 32k = 1024B, lane-linear (l = (kgrp<<4)|row).
template<bool TANH>
__global__ __launch_bounds__(256, 2)
void mfma_gemm(const u16* __restrict__ A, const u16* __restrict__ Wt,
               const float* __restrict__ bias, u16* __restrict__ C,
               int K, int Jreal)
{
  __shared__ __align__(16) u16 sm[2 * 8192];   // [buf][A 4096 u16 | B 4096 u16] = 32 KB
  const int t    = threadIdx.x;
  const int lane = t & 63, w = t >> 6;
  const int wr   = w >> 1, wc = w & 1;
  const int lm   = lane & 15, lk = lane >> 4;
  const int row0 = blockIdx.x * 128;
  const int jb   = blockIdx.y * 128;

  f32x4 acc[4][4];
  #pragma unroll
  for (int i = 0; i < 4; i++)
    #pragma unroll
    for (int j = 0; j < 4; j++) acc[i][j] = (f32x4){0.f, 0.f, 0.f, 0.f};

  const int nk = K >> 5;

  auto stage = [&](int buf, int ks){
    const int kk = ks << 5;
    u16* base = sm + buf * 8192;
    // wave w stages A subtiles {w, w+4} and B subtiles {w, w+4}; LDS dest wave-uniform.
    #pragma unroll
    for (int h = 0; h < 2; h++){
      int s = w + h * 4;
      gload16(A  + (size_t)(row0 + s * 16 + lm) * K + kk + lk * 8, base + s * 512);
      gload16(Wt + (size_t)(jb   + s * 16 + lm) * K + kk + lk * 8, base + 4096 + s * 512);
    }
  };

  auto compute = [&](int buf){
    const u16* base = sm + buf * 8192;
    short8 a[4], b[4];
    #pragma unroll
    for (int i = 0; i < 4; i++){
      a[i] = *(const short8*)(base + (wr * 4 + i) * 512 + lane * 8);
      b[i] = *(const short8*)(base + 4096 + (wc * 4 + i) * 512 + lane * 8);
    }
    #pragma unroll
    for (int i = 0; i < 4; i++)
      #pragma unroll
      for (int j = 0; j < 4; j++)
        acc[i][j] = __builtin_amdgcn_mfma_f32_16x16x32_bf16(a[i], b[j], acc[i][j], 0, 0, 0);
  };

  stage(0, 0);
  __syncthreads();
  for (int ks = 0; ks < nk; ++ks){
    if (ks + 1 < nk) stage((ks + 1) & 1, ks + 1);
    compute(ks & 1);
    __syncthreads();
  }

  // epilogue: C/D layout col = lane&15, row = 4*(lane>>4)+reg  [m89]
  const int rbase = row0 + wr * 64;
  const int cbase = jb + wc * 64;
  #pragma unroll
  for (int j = 0; j < 4; j++){
    int col = cbase + j * 16 + lm;
    if (col < Jreal){
      float bs = bias[col];
      #pragma unroll
      for (int i = 0; i < 4; i++){
        #pragma unroll
        for (int r = 0; r < 4; r++){
          int row = rbase + i * 16 + lk * 4 + r;
          float v = acc[i][j][r] + bs;
          if (TANH) v = tanh_fast(v);
          C[(size_t)row * Jreal + col] = f2bf(v);
        }
      }
    }
  }
}

// x-slice fp32 -> dense bf16 [N][32]
__global__ __launch_bounds__(256)
void xconv_k(const float* __restrict__ in, u16* __restrict__ out, int col0){
  int tid = blockIdx.x * 256 + threadIdx.x;       // N*8 threads
  int row = tid >> 3, c4 = (tid & 7) << 2;
  float4 v = *(const float4*)(in + (size_t)row * NDIM + col0 + c4);
  ushort4 o; o.x = f2bf(v.x); o.y = f2bf(v.y); o.z = f2bf(v.z); o.w = f2bf(v.w);
  *(ushort4*)(out + (size_t)row * NHALF + c4) = o;
}

// W[K x J] fp32 -> Wt[Jpad x K] bf16 transposed; rows >= J zeroed. K = 1<<kshift.
__global__ __launch_bounds__(256)
void wconv_k(const float* __restrict__ W, u16* __restrict__ Wt,
             int kshift, int J, int total){
  int tid = blockIdx.x * 256 + threadIdx.x;
  if (tid >= total) return;
  int n = tid >> kshift, k = tid & ((1 << kshift) - 1);
  Wt[tid] = (n < J) ? f2bf(W[(size_t)k * J + n]) : (u16)0;
}

// ---------------- spline (unchanged from passing R3 version) ----------------
template<int PHASE>
__global__ __launch_bounds__(256)
void spline_k(const float* __restrict__ x,
              const u16* __restrict__ params,
              float* __restrict__ out,
              float* __restrict__ ldp,
              float* __restrict__ ldout,
              int xcol)
{
  __shared__ u16 pb[8 * NPAR];
  const int t = threadIdx.x;
  const int s0 = blockIdx.x * 8;

  {
    const uint4* src = (const uint4*)(params + (size_t)s0 * NPAR);
    uint4* dst = (uint4*)pb;
    dst[t]       = src[t];
    dst[256 + t] = src[256 + t];
    if (t < 224) dst[512 + t] = src[512 + t];
  }
  __syncthreads();

  const int si = t >> 5, d = t & 31;
  const int s = s0 + si;
  const u16* pp = pb + si * NPAR + d * 23;
  float p[23];
  #pragma unroll
  for (int e = 0; e < 23; e++) p[e] = bf2f(pp[e]);

  float W6[8], H6[8];
  {
    float m = p[0];
    #pragma unroll
    for (int i = 1; i < 8; i++) m = fmaxf(m, p[i]);
    float sm = 0.f;
    #pragma unroll
    for (int i = 0; i < 8; i++){ W6[i] = __expf(p[i] - m); sm += W6[i]; }
    float r = 6.f / sm;
    #pragma unroll
    for (int i = 0; i < 8; i++) W6[i] *= r;
  }
  {
    float m = p[8];
    #pragma unroll
    for (int i = 1; i < 8; i++) m = fmaxf(m, p[8 + i]);
    float sm = 0.f;
    #pragma unroll
    for (int i = 0; i < 8; i++){ H6[i] = __expf(p[8 + i] - m); sm += H6[i]; }
    float r = 6.f / sm;
    #pragma unroll
    for (int i = 0; i < 8; i++) H6[i] *= r;
  }

  float wd[8], cumw[9];
  {
    float m = W6[0];
    #pragma unroll
    for (int i = 1; i < 8; i++) m = fmaxf(m, W6[i]);
    float sm = 0.f;
    #pragma unroll
    for (int i = 0; i < 8; i++){ wd[i] = __expf(W6[i] - m); sm += wd[i]; }
    float r = 1.f / sm;
    #pragma unroll
    for (int i = 0; i < 8; i++) wd[i] = 0.001f + 0.992f * wd[i] * r;
  }
  cumw[0] = -3.f;
  { float run = 0.f;
    #pragma unroll
    for (int i = 0; i < 8; i++){ run += wd[i]; cumw[i + 1] = 6.f * run - 3.f; } }
  cumw[8] = 3.f;
  #pragma unroll
  for (int i = 0; i < 8; i++) wd[i] = cumw[i + 1] - cumw[i];

  float hg[8], cumh[9];
  {
    float m = H6[0];
    #pragma unroll
    for (int i = 1; i < 8; i++) m = fmaxf(m, H6[i]);
    float sm = 0.f;
    #pragma unroll
    for (int i = 0; i < 8; i++){ hg[i] = __expf(H6[i] - m); sm += hg[i]; }
    float r = 1.f / sm;
    #pragma unroll
    for (int i = 0; i < 8; i++) hg[i] = 0.001f + 0.992f * hg[i] * r;
  }
  cumh[0] = -3.f;
  { float run = 0.f;
    #pragma unroll
    for (int i = 0; i < 8; i++){ run += hg[i]; cumh[i + 1] = 6.f * run - 3.f; } }
  cumh[8] = 3.f;
  #pragma unroll
  for (int i = 0; i < 8; i++) hg[i] = cumh[i + 1] - cumh[i];

  float dv[9];
  dv[0] = 1.f; dv[8] = 1.f;
  #pragma unroll
  for (int j = 0; j < 7; j++){
    float Dj = softplus_f(p[16 + j]);
    dv[j + 1] = 0.001f + softplus_f(Dj);
  }

  const float xv  = x[(size_t)s * NDIM + xcol + d];
  const float xin = fminf(3.f, fmaxf(-3.f, xv));

  int b = 0;
  #pragma unroll
  for (int j = 1; j < 8; j++) b += (xin >= cumw[j]) ? 1 : 0;

  float in_cw = 0.f, in_w = 0.f, in_ch = 0.f, in_h = 0.f, in_d = 0.f, in_d1 = 0.f;
  #pragma unroll
  for (int j = 0; j < 8; j++){
    if (j == b){ in_cw = cumw[j]; in_w = wd[j]; in_ch = cumh[j];
                 in_h = hg[j];  in_d = dv[j]; in_d1 = dv[j + 1]; }
  }

  float th    = (xin - in_cw) / in_w;
  float tt    = th * (1.f - th);
  float delta = in_h / in_w;
  float numer = in_h * (delta * th * th + in_d * tt);
  float denom = delta + (in_d + in_d1 - 2.f * delta) * tt;
  float outv  = in_ch + numer / denom;
  float omt   = 1.f - th;
  float dnum  = delta * delta * (in_d1 * th * th + 2.f * delta * tt + in_d * omt * omt);
  float lad   = __logf(dnum) - 2.f * __logf(denom);

  bool inside = (xv >= -3.f) && (xv <= 3.f);
  outv = inside ? outv : xv;
  lad  = inside ? lad  : 0.f;

  out[(size_t)s * NDIM + xcol + d] = outv;

  float v = lad;
  #pragma unroll
  for (int mm = 1; mm < 32; mm <<= 1) v += __shfl_xor(v, mm, 64);
  if (d == 0){
    if (PHASE == 0) ldp[s] = v;
    else            ldout[s] = ldp[s] + v;
  }
}

extern "C" void kernel_launch(void* const* d_in, const int* in_sizes, int n_in,
                              void* d_out, int out_size, void* d_ws, size_t ws_size,
                              hipStream_t stream)
{
  const float* x    = (const float*)d_in[0];
  const float* f1w0 = (const float*)d_in[1];
  const float* f1b0 = (const float*)d_in[2];
  const float* f1w1 = (const float*)d_in[3];
  const float* f1b1 = (const float*)d_in[4];
  const float* f1w2 = (const float*)d_in[5];
  const float* f1b2 = (const float*)d_in[6];
  const float* f2w0 = (const float*)d_in[7];
  const float* f2b0 = (const float*)d_in[8];
  const float* f2w1 = (const float*)d_in[9];
  const float* f2b1 = (const float*)d_in[10];
  const float* f2w2 = (const float*)d_in[11];
  const float* f2b2 = (const float*)d_in[12];

  const int N = in_sizes[0] / NDIM;   // 65536
  float* out = (float*)d_out;
  float* ldout = out + (size_t)N * NDIM;

  // ws: h1 (N*256 bf16) | h2 (N*256 bf16) | pr (N*736 bf16) | ld1 (N f32) | wbuf
  // xb (N*32 bf16, 4MB) aliases the START of pr — lifetimes disjoint:
  //   xconv->xb, gemm0 reads xb, then gemm2 overwrites pr; next coupling's xconv
  //   runs only after spline consumed pr.
  u16* h1 = (u16*)d_ws;
  u16* h2 = h1 + (size_t)N * NHID;
  u16* pr = h2 + (size_t)N * NHID;
  float* ld1 = (float*)(pr + (size_t)N * NPAR);
  u16* wb  = (u16*)(ld1 + N);
  u16* w0t = wb;                       // 256 x 32
  u16* w1t = w0t + 256 * 32;           // 256 x 256
  u16* w2t = w1t + 256 * 256;          // 768 x 256 (rows 736.. zero)
  u16* xb  = pr;                       // alias

  dim3 blk(256);
  dim3 g256(N / 128, 2);               // J=256
  dim3 g736(N / 128, 6);               // Jpad=768
  dim3 gx(N * 8 / 256);
  dim3 gs(N / 8);

  // ---- coupling 1
  wconv_k<<<dim3(32),  blk, 0, stream>>>(f1w0, w0t, 5, 256, 256 * 32);
  wconv_k<<<dim3(256), blk, 0, stream>>>(f1w1, w1t, 8, 256, 256 * 256);
  wconv_k<<<dim3(768), blk, 0, stream>>>(f1w2, w2t, 8, 736, 768 * 256);
  xconv_k<<<gx, blk, 0, stream>>>(x, xb, 0);
  mfma_gemm<true ><<<g256, blk, 0, stream>>>(xb, w0t, f1b0, h1, 32,  256);
  mfma_gemm<true ><<<g256, blk, 0, stream>>>(h1, w1t, f1b1, h2, 256, 256);
  mfma_gemm<false><<<g736, blk, 0, stream>>>(h2, w2t, f1b2, pr, 256, 736);
  spline_k<0><<<gs, blk, 0, stream>>>(x, pr, out, ld1, ldout, NHALF);

  // ---- coupling 2
  wconv_k<<<dim3(32),  blk, 0, stream>>>(f2w0, w0t, 5, 256, 256 * 32);
  wconv_k<<<dim3(256), blk, 0, stream>>>(f2w1, w1t, 8, 256, 256 * 256);
  wconv_k<<<dim3(768), blk, 0, stream>>>(f2w2, w2t, 8, 736, 768 * 256);
  xconv_k<<<gx, blk, 0, stream>>>(out, xb, NHALF);
  mfma_gemm<true ><<<g256, blk, 0, stream>>>(xb, w0t, f2b0, h1, 32,  256);
  mfma_gemm<true ><<<g256, blk, 0, stream>>>(h1, w1t, f2b1, h2, 256, 256);
  mfma_gemm<false><<<g736, blk, 0, stream>>>(h2, w2t, f2b2, pr, 256, 736);
  spline_k<1><<<gs, blk, 0, stream>>>(x, pr, out, ld1, ldout, 0);
}

// Round 5
// 387.669 us; speedup vs baseline: 3.0441x; 1.4393x over previous
//
#include <hip/hip_runtime.h>

#define NHALF 32
#define NDIM  64
#define NHID  256
#define NPAR  736   // (3K-1)*HALF = 23*32

typedef unsigned short u16;
typedef unsigned int   u32;
typedef __attribute__((ext_vector_type(8))) short short8;   // 8 bf16 = 4 VGPR
typedef __attribute__((ext_vector_type(4))) float f32x4;

__device__ __forceinline__ float bf2f(u16 h){ return __uint_as_float(((u32)h) << 16); }
__device__ __forceinline__ u16 f2bf(float f){
  u32 u = __float_as_uint(f);
  u += 0x7FFFu + ((u >> 16) & 1u);   // round-to-nearest-even
  return (u16)(u >> 16);
}
__device__ __forceinline__ float frcp(float x){ return __builtin_amdgcn_rcpf(x); }
__device__ __forceinline__ float tanh_fast(float x){
  x = fminf(15.f, fmaxf(-15.f, x));
  float e = __expf(2.f * x);
  return 1.f - 2.f * frcp(e + 1.f);
}

__device__ __forceinline__ void gload16(const u16* g, u16* l){
  __builtin_amdgcn_global_load_lds(
      (const __attribute__((address_space(1))) unsigned int*)(g),
      (__attribute__((address_space(3))) unsigned int*)(l), 16, 0, 0);
}

// ---------------- MFMA GEMM: C[M x Jreal](bf16) = act(A[M x K](bf16) @ Wt^T + bias)
// A dense row-major (lda=K). Wt: bf16 [Jpad][K] (n-major, k-contiguous), rows>=Jreal zeroed.
// 128x128 tile, 4 waves (2x2), per-wave 64x64 = 4x4 frags of 16x16x32.
// LDS fragment-contiguous: subtile = 16(m|n) x 32k = 1024B, lane-linear (l = (kgrp<<4)|row).
template<bool TANH>
__global__ __launch_bounds__(256, 2)
void mfma_gemm(const u16* __restrict__ A, const u16* __restrict__ Wt,
               const float* __restrict__ bias, u16* __restrict__ C,
               int K, int Jreal)
{
  __shared__ __align__(16) u16 sm[2 * 8192];   // [buf][A 4096 u16 | B 4096 u16] = 32 KB
  const int t    = threadIdx.x;
  const int lane = t & 63, w = t >> 6;
  const int wr   = w >> 1, wc = w & 1;
  const int lm   = lane & 15, lk = lane >> 4;
  const int row0 = blockIdx.x * 128;
  const int jb   = blockIdx.y * 128;

  f32x4 acc[4][4];
  #pragma unroll
  for (int i = 0; i < 4; i++)
    #pragma unroll
    for (int j = 0; j < 4; j++) acc[i][j] = (f32x4){0.f, 0.f, 0.f, 0.f};

  const int nk = K >> 5;

  auto stage = [&](int buf, int ks){
    const int kk = ks << 5;
    u16* base = sm + buf * 8192;
    #pragma unroll
    for (int h = 0; h < 2; h++){
      int s = w + h * 4;
      gload16(A  + (size_t)(row0 + s * 16 + lm) * K + kk + lk * 8, base + s * 512);
      gload16(Wt + (size_t)(jb   + s * 16 + lm) * K + kk + lk * 8, base + 4096 + s * 512);
    }
  };

  auto compute = [&](int buf){
    const u16* base = sm + buf * 8192;
    short8 a[4], b[4];
    #pragma unroll
    for (int i = 0; i < 4; i++){
      a[i] = *(const short8*)(base + (wr * 4 + i) * 512 + lane * 8);
      b[i] = *(const short8*)(base + 4096 + (wc * 4 + i) * 512 + lane * 8);
    }
    #pragma unroll
    for (int i = 0; i < 4; i++)
      #pragma unroll
      for (int j = 0; j < 4; j++)
        acc[i][j] = __builtin_amdgcn_mfma_f32_16x16x32_bf16(a[i], b[j], acc[i][j], 0, 0, 0);
  };

  stage(0, 0);
  __syncthreads();
  for (int ks = 0; ks < nk; ++ks){
    if (ks + 1 < nk) stage((ks + 1) & 1, ks + 1);
    compute(ks & 1);
    __syncthreads();
  }

  // epilogue: C/D layout col = lane&15, row = 4*(lane>>4)+reg  [m89]
  const int rbase = row0 + wr * 64;
  const int cbase = jb + wc * 64;
  #pragma unroll
  for (int j = 0; j < 4; j++){
    int col = cbase + j * 16 + lm;
    if (col < Jreal){
      float bs = bias[col];
      #pragma unroll
      for (int i = 0; i < 4; i++){
        #pragma unroll
        for (int r = 0; r < 4; r++){
          int row = rbase + i * 16 + lk * 4 + r;
          float v = acc[i][j][r] + bs;
          if (TANH) v = tanh_fast(v);
          C[(size_t)row * Jreal + col] = f2bf(v);
        }
      }
    }
  }
}

// x-slice fp32 -> dense bf16 [N][32]
__global__ __launch_bounds__(256)
void xconv_k(const float* __restrict__ in, u16* __restrict__ out, int col0){
  int tid = blockIdx.x * 256 + threadIdx.x;       // N*8 threads
  int row = tid >> 3, c4 = (tid & 7) << 2;
  float4 v = *(const float4*)(in + (size_t)row * NDIM + col0 + c4);
  ushort4 o; o.x = f2bf(v.x); o.y = f2bf(v.y); o.z = f2bf(v.z); o.w = f2bf(v.w);
  *(ushort4*)(out + (size_t)row * NHALF + c4) = o;
}

// W[K x J] fp32 -> Wt[Jpad x K] bf16 transposed; rows >= J zeroed. K = 1<<kshift.
__global__ __launch_bounds__(256)
void wconv_k(const float* __restrict__ W, u16* __restrict__ Wt,
             int kshift, int J, int total){
  int tid = blockIdx.x * 256 + threadIdx.x;
  if (tid >= total) return;
  int n = tid >> kshift, k = tid & ((1 << kshift) - 1);
  Wt[tid] = (n < J) ? f2bf(W[(size_t)k * J + n]) : (u16)0;
}

// ---------------- spline: restructured math (R5) ----------------
// Changes vs R3-passing version (math-equivalent, verified):
//  * sp(sp(x)) = max(x,0) + log(1 + e^-|x| + (x>=0 ? e^-|x| : 1))  [no log1pf]
//  * 2nd softmax pair skips max-shift (input in [0,6], sum known bounded)
//  * all divides -> v_rcp_f32;  log(dnum)-2log(denom) -> log(dnum*rden^2)
template<int PHASE>
__global__ __launch_bounds__(256)
void spline_k(const float* __restrict__ x,
              const u16* __restrict__ params,
              float* __restrict__ out,
              float* __restrict__ ldp,
              float* __restrict__ ldout,
              int xcol)
{
  __shared__ u16 pb[8 * NPAR];
  const int t = threadIdx.x;
  const int s0 = blockIdx.x * 8;

  {
    const uint4* src = (const uint4*)(params + (size_t)s0 * NPAR);
    uint4* dst = (uint4*)pb;
    dst[t]       = src[t];
    dst[256 + t] = src[256 + t];
    if (t < 224) dst[512 + t] = src[512 + t];
  }
  __syncthreads();

  const int si = t >> 5, d = t & 31;
  const int s = s0 + si;
  const u16* pp = pb + si * NPAR + d * 23;
  float p[23];
  #pragma unroll
  for (int e = 0; e < 23; e++) p[e] = bf2f(pp[e]);

  // W6 = 6*softmax(p[0:8]), H6 = 6*softmax(p[8:16])  (max-shifted: p unbounded)
  float W6[8], H6[8];
  {
    float m = p[0];
    #pragma unroll
    for (int i = 1; i < 8; i++) m = fmaxf(m, p[i]);
    float sm = 0.f;
    #pragma unroll
    for (int i = 0; i < 8; i++){ W6[i] = __expf(p[i] - m); sm += W6[i]; }
    float r = 6.f * frcp(sm);
    #pragma unroll
    for (int i = 0; i < 8; i++) W6[i] *= r;
  }
  {
    float m = p[8];
    #pragma unroll
    for (int i = 1; i < 8; i++) m = fmaxf(m, p[8 + i]);
    float sm = 0.f;
    #pragma unroll
    for (int i = 0; i < 8; i++){ H6[i] = __expf(p[8 + i] - m); sm += H6[i]; }
    float r = 6.f * frcp(sm);
    #pragma unroll
    for (int i = 0; i < 8; i++) H6[i] *= r;
  }

  // widths = 0.001 + 0.992*softmax(W6): W6 in [0,6] -> no max-shift needed
  float wd[8], cumw[9];
  {
    float sm = 0.f;
    #pragma unroll
    for (int i = 0; i < 8; i++){ wd[i] = __expf(W6[i]); sm += wd[i]; }
    float r = 0.992f * frcp(sm);
    #pragma unroll
    for (int i = 0; i < 8; i++) wd[i] = 0.001f + wd[i] * r;
  }
  cumw[0] = -3.f;
  { float run = 0.f;
    #pragma unroll
    for (int i = 0; i < 8; i++){ run += wd[i]; cumw[i + 1] = 6.f * run - 3.f; } }
  cumw[8] = 3.f;
  #pragma unroll
  for (int i = 0; i < 8; i++) wd[i] = cumw[i + 1] - cumw[i];

  float hg[8], cumh[9];
  {
    float sm = 0.f;
    #pragma unroll
    for (int i = 0; i < 8; i++){ hg[i] = __expf(H6[i]); sm += hg[i]; }
    float r = 0.992f * frcp(sm);
    #pragma unroll
    for (int i = 0; i < 8; i++) hg[i] = 0.001f + hg[i] * r;
  }
  cumh[0] = -3.f;
  { float run = 0.f;
    #pragma unroll
    for (int i = 0; i < 8; i++){ run += hg[i]; cumh[i + 1] = 6.f * run - 3.f; } }
  cumh[8] = 3.f;
  #pragma unroll
  for (int i = 0; i < 8; i++) hg[i] = cumh[i + 1] - cumh[i];

  // dv[j+1] = 0.001 + sp(sp(p16j)); fused: max(x,0) + log(1 + z + (x>=0 ? z : 1)), z=e^-|x|
  float dv[9];
  dv[0] = 1.f; dv[8] = 1.f;
  #pragma unroll
  for (int j = 0; j < 7; j++){
    float xx  = p[16 + j];
    float z   = __expf(-fabsf(xx));
    float sel = (xx >= 0.f) ? z : 1.f;
    dv[j + 1] = 0.001f + fmaxf(xx, 0.f) + __logf(1.f + z + sel);
  }

  const float xv  = x[(size_t)s * NDIM + xcol + d];
  const float xin = fminf(3.f, fmaxf(-3.f, xv));

  int b = 0;
  #pragma unroll
  for (int j = 1; j < 8; j++) b += (xin >= cumw[j]) ? 1 : 0;

  float in_cw = 0.f, in_w = 0.f, in_ch = 0.f, in_h = 0.f, in_d = 0.f, in_d1 = 0.f;
  #pragma unroll
  for (int j = 0; j < 8; j++){
    if (j == b){ in_cw = cumw[j]; in_w = wd[j]; in_ch = cumh[j];
                 in_h = hg[j];  in_d = dv[j]; in_d1 = dv[j + 1]; }
  }

  float rw    = frcp(in_w);
  float th    = (xin - in_cw) * rw;
  float tt    = th * (1.f - th);
  float delta = in_h * rw;
  float numer = in_h * (delta * th * th + in_d * tt);
  float denom = delta + (in_d + in_d1 - 2.f * delta) * tt;
  float rden  = frcp(denom);
  float outv  = in_ch + numer * rden;
  float omt   = 1.f - th;
  float dnum  = delta * delta * (in_d1 * th * th + 2.f * delta * tt + in_d * omt * omt);
  float lad   = __logf(dnum * rden * rden);

  bool inside = (xv >= -3.f) && (xv <= 3.f);
  outv = inside ? outv : xv;
  lad  = inside ? lad  : 0.f;

  out[(size_t)s * NDIM + xcol + d] = outv;

  float v = lad;
  #pragma unroll
  for (int mm = 1; mm < 32; mm <<= 1) v += __shfl_xor(v, mm, 64);
  if (d == 0){
    if (PHASE == 0) ldp[s] = v;
    else            ldout[s] = ldp[s] + v;
  }
}

extern "C" void kernel_launch(void* const* d_in, const int* in_sizes, int n_in,
                              void* d_out, int out_size, void* d_ws, size_t ws_size,
                              hipStream_t stream)
{
  const float* x    = (const float*)d_in[0];
  const float* f1w0 = (const float*)d_in[1];
  const float* f1b0 = (const float*)d_in[2];
  const float* f1w1 = (const float*)d_in[3];
  const float* f1b1 = (const float*)d_in[4];
  const float* f1w2 = (const float*)d_in[5];
  const float* f1b2 = (const float*)d_in[6];
  const float* f2w0 = (const float*)d_in[7];
  const float* f2b0 = (const float*)d_in[8];
  const float* f2w1 = (const float*)d_in[9];
  const float* f2b1 = (const float*)d_in[10];
  const float* f2w2 = (const float*)d_in[11];
  const float* f2b2 = (const float*)d_in[12];

  const int N = in_sizes[0] / NDIM;   // 65536
  float* out = (float*)d_out;
  float* ldout = out + (size_t)N * NDIM;

  u16* h1 = (u16*)d_ws;
  u16* h2 = h1 + (size_t)N * NHID;
  u16* pr = h2 + (size_t)N * NHID;
  float* ld1 = (float*)(pr + (size_t)N * NPAR);
  u16* wb  = (u16*)(ld1 + N);
  u16* w0t = wb;                       // 256 x 32
  u16* w1t = w0t + 256 * 32;           // 256 x 256
  u16* w2t = w1t + 256 * 256;          // 768 x 256 (rows 736.. zero)
  u16* xb  = pr;                       // alias (lifetimes disjoint)

  dim3 blk(256);
  dim3 g256(N / 128, 2);               // J=256
  dim3 g736(N / 128, 6);               // Jpad=768
  dim3 gx(N * 8 / 256);
  dim3 gs(N / 8);

  // ---- coupling 1
  wconv_k<<<dim3(32),  blk, 0, stream>>>(f1w0, w0t, 5, 256, 256 * 32);
  wconv_k<<<dim3(256), blk, 0, stream>>>(f1w1, w1t, 8, 256, 256 * 256);
  wconv_k<<<dim3(768), blk, 0, stream>>>(f1w2, w2t, 8, 736, 768 * 256);
  xconv_k<<<gx, blk, 0, stream>>>(x, xb, 0);
  mfma_gemm<true ><<<g256, blk, 0, stream>>>(xb, w0t, f1b0, h1, 32,  256);
  mfma_gemm<true ><<<g256, blk, 0, stream>>>(h1, w1t, f1b1, h2, 256, 256);
  mfma_gemm<false><<<g736, blk, 0, stream>>>(h2, w2t, f1b2, pr, 256, 736);
  spline_k<0><<<gs, blk, 0, stream>>>(x, pr, out, ld1, ldout, NHALF);

  // ---- coupling 2
  wconv_k<<<dim3(32),  blk, 0, stream>>>(f2w0, w0t, 5, 256, 256 * 32);
  wconv_k<<<dim3(256), blk, 0, stream>>>(f2w1, w1t, 8, 256, 256 * 256);
  wconv_k<<<dim3(768), blk, 0, stream>>>(f2w2, w2t, 8, 736, 768 * 256);
  xconv_k<<<gx, blk, 0, stream>>>(out, xb, NHALF);
  mfma_gemm<true ><<<g256, blk, 0, stream>>>(xb, w0t, f2b0, h1, 32,  256);
  mfma_gemm<true ><<<g256, blk, 0, stream>>>(h1, w1t, f2b1, h2, 256, 256);
  mfma_gemm<false><<<g736, blk, 0, stream>>>(h2, w2t, f2b2, pr, 256, 736);
  spline_k<1><<<gs, blk, 0, stream>>>(x, pr, out, ld1, ldout, 0);
}

// Round 6
// 356.575 us; speedup vs baseline: 3.3095x; 1.0872x over previous
//
#include <hip/hip_runtime.h>

#define NHALF 32
#define NDIM  64
#define NHID  256
#define NPAR  736   // (3K-1)*HALF = 23*32

typedef unsigned short u16;
typedef unsigned int   u32;
typedef __attribute__((ext_vector_type(8))) short short8;   // 8 bf16 = 4 VGPR
typedef __attribute__((ext_vector_type(4))) float f32x4;

__device__ __forceinline__ float bf2f(u16 h){ return __uint_as_float(((u32)h) << 16); }
__device__ __forceinline__ u16 f2bf(float f){
  u32 u = __float_as_uint(f);
  u += 0x7FFFu + ((u >> 16) & 1u);   // round-to-nearest-even
  return (u16)(u >> 16);
}
__device__ __forceinline__ float frcp(float x){ return __builtin_amdgcn_rcpf(x); }
__device__ __forceinline__ float tanh_fast(float x){
  x = fminf(15.f, fmaxf(-15.f, x));
  float e = __expf(2.f * x);
  return 1.f - 2.f * frcp(e + 1.f);
}

__device__ __forceinline__ void gload16(const u16* g, u16* l){
  __builtin_amdgcn_global_load_lds(
      (const __attribute__((address_space(1))) unsigned int*)(g),
      (__attribute__((address_space(3))) unsigned int*)(l), 16, 0, 0);
}

// ---------------- MFMA GEMM: C[M x Jreal](bf16) = act(A[M x K](bf16) @ Wt^T + bias)
// A dense row-major (lda=K). Wt: bf16 [Jpad][K] (n-major, k-contiguous), rows>=Jreal zeroed.
// 128x128 tile, 4 waves (2x2), per-wave 64x64 = 4x4 frags of 16x16x32.
// LDS fragment-contiguous: subtile = 16(m|n) x 32k = 1024B, lane-linear.
// R6: launch_bounds(256,4) -> 4 blocks/CU (was 2); epilogue via LDS transpose
// for 128B-contiguous dwordx4 C stores (was scattered 2B stores, 1.5x write amp).
template<bool TANH>
__global__ __launch_bounds__(256, 4)
void mfma_gemm(const u16* __restrict__ A, const u16* __restrict__ Wt,
               const float* __restrict__ bias, u16* __restrict__ C,
               int K, int Jreal)
{
  // staging: [buf][A 4096 u16 | B 4096 u16] = 32KB (u16[0..16384))
  // epilogue reuse: 4 waves x [64][72] bf16 = 18432 u16 = 36.9KB total
  __shared__ __align__(16) u16 sm[18432];
  const int t    = threadIdx.x;
  const int lane = t & 63, w = t >> 6;
  const int wr   = w >> 1, wc = w & 1;
  const int lm   = lane & 15, lk = lane >> 4;
  const int row0 = blockIdx.x * 128;
  const int jb   = blockIdx.y * 128;

  f32x4 acc[4][4];
  #pragma unroll
  for (int i = 0; i < 4; i++)
    #pragma unroll
    for (int j = 0; j < 4; j++) acc[i][j] = (f32x4){0.f, 0.f, 0.f, 0.f};

  const int nk = K >> 5;

  auto stage = [&](int buf, int ks){
    const int kk = ks << 5;
    u16* base = sm + buf * 8192;
    #pragma unroll
    for (int h = 0; h < 2; h++){
      int s = w + h * 4;
      gload16(A  + (size_t)(row0 + s * 16 + lm) * K + kk + lk * 8, base + s * 512);
      gload16(Wt + (size_t)(jb   + s * 16 + lm) * K + kk + lk * 8, base + 4096 + s * 512);
    }
  };

  auto compute = [&](int buf){
    const u16* base = sm + buf * 8192;
    short8 a[4], b[4];
    #pragma unroll
    for (int i = 0; i < 4; i++){
      a[i] = *(const short8*)(base + (wr * 4 + i) * 512 + lane * 8);
      b[i] = *(const short8*)(base + 4096 + (wc * 4 + i) * 512 + lane * 8);
    }
    #pragma unroll
    for (int i = 0; i < 4; i++)
      #pragma unroll
      for (int j = 0; j < 4; j++)
        acc[i][j] = __builtin_amdgcn_mfma_f32_16x16x32_bf16(a[i], b[j], acc[i][j], 0, 0, 0);
  };

  stage(0, 0);
  __syncthreads();
  for (int ks = 0; ks < nk; ++ks){
    if (ks + 1 < nk) stage((ks + 1) & 1, ks + 1);
    compute(ks & 1);
    __syncthreads();
  }

  // ---- epilogue: wave-private LDS transpose, then coalesced dwordx4 stores.
  // C/D frag layout: local row = i*16 + lk*4 + r, local col = j*16 + lm  [m89]
  const int rbase = row0 + wr * 64;
  const int cbase = jb + wc * 64;
  u16* ep = sm + w * 4608;                  // [64][72] bf16, wave-private
  #pragma unroll
  for (int j = 0; j < 4; j++){
    int col = cbase + j * 16 + lm;
    float bs = (col < Jreal) ? bias[col] : 0.f;
    #pragma unroll
    for (int i = 0; i < 4; i++){
      #pragma unroll
      for (int r = 0; r < 4; r++){
        float v = acc[i][j][r] + bs;
        if (TANH) v = tanh_fast(v);
        ep[(i * 16 + lk * 4 + r) * 72 + j * 16 + lm] = f2bf(v);
      }
    }
  }
  const int lr8 = lane >> 3, lc8 = lane & 7;
  #pragma unroll
  for (int rr = 0; rr < 8; rr++){
    int lr = rr * 8 + lr8;
    uint4 v = *(const uint4*)(ep + lr * 72 + lc8 * 8);
    int col0 = cbase + lc8 * 8;
    if (col0 + 7 < Jreal)
      *(uint4*)(C + (size_t)(rbase + lr) * Jreal + col0) = v;
  }
}

// x-slice fp32 -> dense bf16 [N][32]
__global__ __launch_bounds__(256)
void xconv_k(const float* __restrict__ in, u16* __restrict__ out, int col0){
  int tid = blockIdx.x * 256 + threadIdx.x;       // N*8 threads
  int row = tid >> 3, c4 = (tid & 7) << 2;
  float4 v = *(const float4*)(in + (size_t)row * NDIM + col0 + c4);
  ushort4 o; o.x = f2bf(v.x); o.y = f2bf(v.y); o.z = f2bf(v.z); o.w = f2bf(v.w);
  *(ushort4*)(out + (size_t)row * NHALF + c4) = o;
}

// W[K x J] fp32 -> Wt[Jpad x K] bf16 transposed; rows >= J zeroed. K = 1<<kshift.
__global__ __launch_bounds__(256)
void wconv_k(const float* __restrict__ W, u16* __restrict__ Wt,
             int kshift, int J, int total){
  int tid = blockIdx.x * 256 + threadIdx.x;
  if (tid >= total) return;
  int n = tid >> kshift, k = tid & ((1 << kshift) - 1);
  Wt[tid] = (n < J) ? f2bf(W[(size_t)k * J + n]) : (u16)0;
}

// ---------------- spline (byte-identical to passing R5 version) ----------------
template<int PHASE>
__global__ __launch_bounds__(256)
void spline_k(const float* __restrict__ x,
              const u16* __restrict__ params,
              float* __restrict__ out,
              float* __restrict__ ldp,
              float* __restrict__ ldout,
              int xcol)
{
  __shared__ u16 pb[8 * NPAR];
  const int t = threadIdx.x;
  const int s0 = blockIdx.x * 8;

  {
    const uint4* src = (const uint4*)(params + (size_t)s0 * NPAR);
    uint4* dst = (uint4*)pb;
    dst[t]       = src[t];
    dst[256 + t] = src[256 + t];
    if (t < 224) dst[512 + t] = src[512 + t];
  }
  __syncthreads();

  const int si = t >> 5, d = t & 31;
  const int s = s0 + si;
  const u16* pp = pb + si * NPAR + d * 23;
  float p[23];
  #pragma unroll
  for (int e = 0; e < 23; e++) p[e] = bf2f(pp[e]);

  // W6 = 6*softmax(p[0:8]), H6 = 6*softmax(p[8:16])  (max-shifted: p unbounded)
  float W6[8], H6[8];
  {
    float m = p[0];
    #pragma unroll
    for (int i = 1; i < 8; i++) m = fmaxf(m, p[i]);
    float sm = 0.f;
    #pragma unroll
    for (int i = 0; i < 8; i++){ W6[i] = __expf(p[i] - m); sm += W6[i]; }
    float r = 6.f * frcp(sm);
    #pragma unroll
    for (int i = 0; i < 8; i++) W6[i] *= r;
  }
  {
    float m = p[8];
    #pragma unroll
    for (int i = 1; i < 8; i++) m = fmaxf(m, p[8 + i]);
    float sm = 0.f;
    #pragma unroll
    for (int i = 0; i < 8; i++){ H6[i] = __expf(p[8 + i] - m); sm += H6[i]; }
    float r = 6.f * frcp(sm);
    #pragma unroll
    for (int i = 0; i < 8; i++) H6[i] *= r;
  }

  // widths = 0.001 + 0.992*softmax(W6): W6 in [0,6] -> no max-shift needed
  float wd[8], cumw[9];
  {
    float sm = 0.f;
    #pragma unroll
    for (int i = 0; i < 8; i++){ wd[i] = __expf(W6[i]); sm += wd[i]; }
    float r = 0.992f * frcp(sm);
    #pragma unroll
    for (int i = 0; i < 8; i++) wd[i] = 0.001f + wd[i] * r;
  }
  cumw[0] = -3.f;
  { float run = 0.f;
    #pragma unroll
    for (int i = 0; i < 8; i++){ run += wd[i]; cumw[i + 1] = 6.f * run - 3.f; } }
  cumw[8] = 3.f;
  #pragma unroll
  for (int i = 0; i < 8; i++) wd[i] = cumw[i + 1] - cumw[i];

  float hg[8], cumh[9];
  {
    float sm = 0.f;
    #pragma unroll
    for (int i = 0; i < 8; i++){ hg[i] = __expf(H6[i]); sm += hg[i]; }
    float r = 0.992f * frcp(sm);
    #pragma unroll
    for (int i = 0; i < 8; i++) hg[i] = 0.001f + hg[i] * r;
  }
  cumh[0] = -3.f;
  { float run = 0.f;
    #pragma unroll
    for (int i = 0; i < 8; i++){ run += hg[i]; cumh[i + 1] = 6.f * run - 3.f; } }
  cumh[8] = 3.f;
  #pragma unroll
  for (int i = 0; i < 8; i++) hg[i] = cumh[i + 1] - cumh[i];

  // dv[j+1] = 0.001 + sp(sp(p16j)); fused: max(x,0) + log(1 + z + (x>=0 ? z : 1)), z=e^-|x|
  float dv[9];
  dv[0] = 1.f; dv[8] = 1.f;
  #pragma unroll
  for (int j = 0; j < 7; j++){
    float xx  = p[16 + j];
    float z   = __expf(-fabsf(xx));
    float sel = (xx >= 0.f) ? z : 1.f;
    dv[j + 1] = 0.001f + fmaxf(xx, 0.f) + __logf(1.f + z + sel);
  }

  const float xv  = x[(size_t)s * NDIM + xcol + d];
  const float xin = fminf(3.f, fmaxf(-3.f, xv));

  int b = 0;
  #pragma unroll
  for (int j = 1; j < 8; j++) b += (xin >= cumw[j]) ? 1 : 0;

  float in_cw = 0.f, in_w = 0.f, in_ch = 0.f, in_h = 0.f, in_d = 0.f, in_d1 = 0.f;
  #pragma unroll
  for (int j = 0; j < 8; j++){
    if (j == b){ in_cw = cumw[j]; in_w = wd[j]; in_ch = cumh[j];
                 in_h = hg[j];  in_d = dv[j]; in_d1 = dv[j + 1]; }
  }

  float rw    = frcp(in_w);
  float th    = (xin - in_cw) * rw;
  float tt    = th * (1.f - th);
  float delta = in_h * rw;
  float numer = in_h * (delta * th * th + in_d * tt);
  float denom = delta + (in_d + in_d1 - 2.f * delta) * tt;
  float rden  = frcp(denom);
  float outv  = in_ch + numer * rden;
  float omt   = 1.f - th;
  float dnum  = delta * delta * (in_d1 * th * th + 2.f * delta * tt + in_d * omt * omt);
  float lad   = __logf(dnum * rden * rden);

  bool inside = (xv >= -3.f) && (xv <= 3.f);
  outv = inside ? outv : xv;
  lad  = inside ? lad  : 0.f;

  out[(size_t)s * NDIM + xcol + d] = outv;

  float v = lad;
  #pragma unroll
  for (int mm = 1; mm < 32; mm <<= 1) v += __shfl_xor(v, mm, 64);
  if (d == 0){
    if (PHASE == 0) ldp[s] = v;
    else            ldout[s] = ldp[s] + v;
  }
}

extern "C" void kernel_launch(void* const* d_in, const int* in_sizes, int n_in,
                              void* d_out, int out_size, void* d_ws, size_t ws_size,
                              hipStream_t stream)
{
  const float* x    = (const float*)d_in[0];
  const float* f1w0 = (const float*)d_in[1];
  const float* f1b0 = (const float*)d_in[2];
  const float* f1w1 = (const float*)d_in[3];
  const float* f1b1 = (const float*)d_in[4];
  const float* f1w2 = (const float*)d_in[5];
  const float* f1b2 = (const float*)d_in[6];
  const float* f2w0 = (const float*)d_in[7];
  const float* f2b0 = (const float*)d_in[8];
  const float* f2w1 = (const float*)d_in[9];
  const float* f2b1 = (const float*)d_in[10];
  const float* f2w2 = (const float*)d_in[11];
  const float* f2b2 = (const float*)d_in[12];

  const int N = in_sizes[0] / NDIM;   // 65536
  float* out = (float*)d_out;
  float* ldout = out + (size_t)N * NDIM;

  u16* h1 = (u16*)d_ws;
  u16* h2 = h1 + (size_t)N * NHID;
  u16* pr = h2 + (size_t)N * NHID;
  float* ld1 = (float*)(pr + (size_t)N * NPAR);
  u16* wb  = (u16*)(ld1 + N);
  u16* w0t = wb;                       // 256 x 32
  u16* w1t = w0t + 256 * 32;           // 256 x 256
  u16* w2t = w1t + 256 * 256;          // 768 x 256 (rows 736.. zero)
  u16* xb  = pr;                       // alias (lifetimes disjoint)

  dim3 blk(256);
  dim3 g256(N / 128, 2);               // J=256
  dim3 g736(N / 128, 6);               // Jpad=768
  dim3 gx(N * 8 / 256);
  dim3 gs(N / 8);

  // ---- coupling 1
  wconv_k<<<dim3(32),  blk, 0, stream>>>(f1w0, w0t, 5, 256, 256 * 32);
  wconv_k<<<dim3(256), blk, 0, stream>>>(f1w1, w1t, 8, 256, 256 * 256);
  wconv_k<<<dim3(768), blk, 0, stream>>>(f1w2, w2t, 8, 736, 768 * 256);
  xconv_k<<<gx, blk, 0, stream>>>(x, xb, 0);
  mfma_gemm<true ><<<g256, blk, 0, stream>>>(xb, w0t, f1b0, h1, 32,  256);
  mfma_gemm<true ><<<g256, blk, 0, stream>>>(h1, w1t, f1b1, h2, 256, 256);
  mfma_gemm<false><<<g736, blk, 0, stream>>>(h2, w2t, f1b2, pr, 256, 736);
  spline_k<0><<<gs, blk, 0, stream>>>(x, pr, out, ld1, ldout, NHALF);

  // ---- coupling 2
  wconv_k<<<dim3(32),  blk, 0, stream>>>(f2w0, w0t, 5, 256, 256 * 32);
  wconv_k<<<dim3(256), blk, 0, stream>>>(f2w1, w1t, 8, 256, 256 * 256);
  wconv_k<<<dim3(768), blk, 0, stream>>>(f2w2, w2t, 8, 736, 768 * 256);
  xconv_k<<<gx, blk, 0, stream>>>(out, xb, NHALF);
  mfma_gemm<true ><<<g256, blk, 0, stream>>>(xb, w0t, f2b0, h1, 32,  256);
  mfma_gemm<true ><<<g256, blk, 0, stream>>>(h1, w1t, f2b1, h2, 256, 256);
  mfma_gemm<false><<<g736, blk, 0, stream>>>(h2, w2t, f2b2, pr, 256, 736);
  spline_k<1><<<gs, blk, 0, stream>>>(x, pr, out, ld1, ldout, 0);
}

// Round 8
// 354.186 us; speedup vs baseline: 3.3318x; 1.0067x over previous
//
#include <hip/hip_runtime.h>

#define NHALF 32
#define NDIM  64
#define NHID  256
#define NPAR  736   // (3K-1)*HALF = 23*32

typedef unsigned short u16;
typedef unsigned int   u32;
typedef __attribute__((ext_vector_type(8))) short short8;   // 8 bf16 = 4 VGPR
typedef __attribute__((ext_vector_type(4))) float f32x4;

__device__ __forceinline__ float bf2f(u16 h){ return __uint_as_float(((u32)h) << 16); }
__device__ __forceinline__ u16 f2bf(float f){
  u32 u = __float_as_uint(f);
  u += 0x7FFFu + ((u >> 16) & 1u);   // round-to-nearest-even
  return (u16)(u >> 16);
}
__device__ __forceinline__ float frcp(float x){ return __builtin_amdgcn_rcpf(x); }
__device__ __forceinline__ float tanh_fast(float x){
  x = fminf(15.f, fmaxf(-15.f, x));
  float e = __expf(2.f * x);
  return 1.f - 2.f * frcp(e + 1.f);
}

__device__ __forceinline__ void gload16(const u16* g, u16* l){
  __builtin_amdgcn_global_load_lds(
      (const __attribute__((address_space(1))) unsigned int*)(g),
      (__attribute__((address_space(3))) unsigned int*)(l), 16, 0, 0);
}

// ---------------- MFMA GEMM: C[M x Jreal](bf16) = act(A[M x K](bf16) @ Wt^T + bias)
// A dense row-major (lda=K). Wt: bf16 [Jpad][K] (n-major, k-contiguous), rows>=Jreal zeroed.
// 128x128 tile, 4 waves (2x2), per-wave 64x64 = 4x4 frags of 16x16x32.
// R7: LDS trimmed to exactly 32768B (staging 2x16KB; epilogue overlays staging in
// two 32-row halves, [32][76] u16 per wave) -> target 4 blocks/CU (16 waves = the
// 50% cap set by 56 VGPR + 64 acc AGPR = 120 regs -> 4 waves/SIMD).
// 76-u16 row stride kills the 8-way readback bank conflict seen in R6 (360K).
template<bool TANH>
__global__ __launch_bounds__(256, 4)
void mfma_gemm(const u16* __restrict__ A, const u16* __restrict__ Wt,
               const float* __restrict__ bias, u16* __restrict__ C,
               int K, int Jreal)
{
  __shared__ __align__(16) u16 sm[16384];   // 32768 B exactly
  const int t    = threadIdx.x;
  const int lane = t & 63, w = t >> 6;
  const int wr   = w >> 1, wc = w & 1;
  const int lm   = lane & 15, lk = lane >> 4;
  const int row0 = blockIdx.x * 128;
  const int jb   = blockIdx.y * 128;

  f32x4 acc[4][4];
  #pragma unroll
  for (int i = 0; i < 4; i++)
    #pragma unroll
    for (int j = 0; j < 4; j++) acc[i][j] = (f32x4){0.f, 0.f, 0.f, 0.f};

  const int nk = K >> 5;

  auto stage = [&](int buf, int ks){
    const int kk = ks << 5;
    u16* base = sm + buf * 8192;
    #pragma unroll
    for (int h = 0; h < 2; h++){
      int s = w + h * 4;
      gload16(A  + (size_t)(row0 + s * 16 + lm) * K + kk + lk * 8, base + s * 512);
      gload16(Wt + (size_t)(jb   + s * 16 + lm) * K + kk + lk * 8, base + 4096 + s * 512);
    }
  };

  auto compute = [&](int buf){
    const u16* base = sm + buf * 8192;
    short8 a[4], b[4];
    #pragma unroll
    for (int i = 0; i < 4; i++){
      a[i] = *(const short8*)(base + (wr * 4 + i) * 512 + lane * 8);
      b[i] = *(const short8*)(base + 4096 + (wc * 4 + i) * 512 + lane * 8);
    }
    #pragma unroll
    for (int i = 0; i < 4; i++)
      #pragma unroll
      for (int j = 0; j < 4; j++)
        acc[i][j] = __builtin_amdgcn_mfma_f32_16x16x32_bf16(a[i], b[j], acc[i][j], 0, 0, 0);
  };

  stage(0, 0);
  __syncthreads();
  for (int ks = 0; ks < nk; ++ks){
    if (ks + 1 < nk) stage((ks + 1) & 1, ks + 1);
    compute(ks & 1);
    __syncthreads();   // final barrier also protects epilogue overlay of staging LDS
  }

  // ---- epilogue: two 32-row halves through wave-private [32][76] LDS, then
  // coalesced 128B-contiguous dwordx4 row stores.
  const int rbase = row0 + wr * 64;
  const int cbase = jb + wc * 64;
  u16* ep = sm + w * 2432;                  // 4864 B per wave
  float bs[4];
  #pragma unroll
  for (int j = 0; j < 4; j++){
    int col = cbase + j * 16 + lm;
    bs[j] = (col < Jreal) ? bias[col] : 0.f;
  }
  const int lr8 = lane >> 3, lc8 = lane & 7;
  #pragma unroll
  for (int h = 0; h < 2; h++){
    #pragma unroll
    for (int ii = 0; ii < 2; ii++){
      int i = h * 2 + ii;
      #pragma unroll
      for (int j = 0; j < 4; j++){
        #pragma unroll
        for (int r = 0; r < 4; r++){
          float v = acc[i][j][r] + bs[j];
          if (TANH) v = tanh_fast(v);
          ep[(ii * 16 + lk * 4 + r) * 76 + j * 16 + lm] = f2bf(v);
        }
      }
    }
    #pragma unroll
    for (int pass = 0; pass < 4; pass++){
      int lr = pass * 8 + lr8;
      uint4 v = *(const uint4*)(ep + lr * 76 + lc8 * 8);
      int col0 = cbase + lc8 * 8;
      if (col0 + 7 < Jreal)
        *(uint4*)(C + (size_t)(rbase + h * 32 + lr) * Jreal + col0) = v;
    }
  }
}

// x-slice fp32 -> dense bf16 [N][32]
__global__ __launch_bounds__(256)
void xconv_k(const float* __restrict__ in, u16* __restrict__ out, int col0){
  int tid = blockIdx.x * 256 + threadIdx.x;       // N*8 threads
  int row = tid >> 3, c4 = (tid & 7) << 2;
  float4 v = *(const float4*)(in + (size_t)row * NDIM + col0 + c4);
  ushort4 o; o.x = f2bf(v.x); o.y = f2bf(v.y); o.z = f2bf(v.z); o.w = f2bf(v.w);
  *(ushort4*)(out + (size_t)row * NHALF + c4) = o;
}

// All three weight conversions in one launch.
// seg0: w0t[256x32] from W0[32x256]; seg1: w1t[256x256] from W1[256x256];
// seg2: w2t[768x256] from W2[256x736] (rows >=736 zeroed).
__global__ __launch_bounds__(256)
void wconv3_k(const float* __restrict__ W0, const float* __restrict__ W1,
              const float* __restrict__ W2,
              u16* __restrict__ w0t, u16* __restrict__ w1t, u16* __restrict__ w2t){
  int tid = blockIdx.x * 256 + threadIdx.x;
  if (tid < 8192){
    int n = tid >> 5, k = tid & 31;
    w0t[tid] = f2bf(W0[(size_t)k * 256 + n]);
  } else if (tid < 73728){
    int id = tid - 8192; int n = id >> 8, k = id & 255;
    w1t[id] = f2bf(W1[(size_t)k * 256 + n]);
  } else if (tid < 270336){
    int id = tid - 73728; int n = id >> 8, k = id & 255;
    w2t[id] = (n < 736) ? f2bf(W2[(size_t)k * 736 + n]) : (u16)0;
  }
}

// ---------------- spline (byte-identical to passing R5/R6 version) ----------------
template<int PHASE>
__global__ __launch_bounds__(256)
void spline_k(const float* __restrict__ x,
              const u16* __restrict__ params,
              float* __restrict__ out,
              float* __restrict__ ldp,
              float* __restrict__ ldout,
              int xcol)
{
  __shared__ u16 pb[8 * NPAR];
  const int t = threadIdx.x;
  const int s0 = blockIdx.x * 8;

  {
    const uint4* src = (const uint4*)(params + (size_t)s0 * NPAR);
    uint4* dst = (uint4*)pb;
    dst[t]       = src[t];
    dst[256 + t] = src[256 + t];
    if (t < 224) dst[512 + t] = src[512 + t];
  }
  __syncthreads();

  const int si = t >> 5, d = t & 31;
  const int s = s0 + si;
  const u16* pp = pb + si * NPAR + d * 23;
  float p[23];
  #pragma unroll
  for (int e = 0; e < 23; e++) p[e] = bf2f(pp[e]);

  float W6[8], H6[8];
  {
    float m = p[0];
    #pragma unroll
    for (int i = 1; i < 8; i++) m = fmaxf(m, p[i]);
    float sm = 0.f;
    #pragma unroll
    for (int i = 0; i < 8; i++){ W6[i] = __expf(p[i] - m); sm += W6[i]; }
    float r = 6.f * frcp(sm);
    #pragma unroll
    for (int i = 0; i < 8; i++) W6[i] *= r;
  }
  {
    float m = p[8];
    #pragma unroll
    for (int i = 1; i < 8; i++) m = fmaxf(m, p[8 + i]);
    float sm = 0.f;
    #pragma unroll
    for (int i = 0; i < 8; i++){ H6[i] = __expf(p[8 + i] - m); sm += H6[i]; }
    float r = 6.f * frcp(sm);
    #pragma unroll
    for (int i = 0; i < 8; i++) H6[i] *= r;
  }

  float wd[8], cumw[9];
  {
    float sm = 0.f;
    #pragma unroll
    for (int i = 0; i < 8; i++){ wd[i] = __expf(W6[i]); sm += wd[i]; }
    float r = 0.992f * frcp(sm);
    #pragma unroll
    for (int i = 0; i < 8; i++) wd[i] = 0.001f + wd[i] * r;
  }
  cumw[0] = -3.f;
  { float run = 0.f;
    #pragma unroll
    for (int i = 0; i < 8; i++){ run += wd[i]; cumw[i + 1] = 6.f * run - 3.f; } }
  cumw[8] = 3.f;
  #pragma unroll
  for (int i = 0; i < 8; i++) wd[i] = cumw[i + 1] - cumw[i];

  float hg[8], cumh[9];
  {
    float sm = 0.f;
    #pragma unroll
    for (int i = 0; i < 8; i++){ hg[i] = __expf(H6[i]); sm += hg[i]; }
    float r = 0.992f * frcp(sm);
    #pragma unroll
    for (int i = 0; i < 8; i++) hg[i] = 0.001f + hg[i] * r;
  }
  cumh[0] = -3.f;
  { float run = 0.f;
    #pragma unroll
    for (int i = 0; i < 8; i++){ run += hg[i]; cumh[i + 1] = 6.f * run - 3.f; } }
  cumh[8] = 3.f;
  #pragma unroll
  for (int i = 0; i < 8; i++) hg[i] = cumh[i + 1] - cumh[i];

  float dv[9];
  dv[0] = 1.f; dv[8] = 1.f;
  #pragma unroll
  for (int j = 0; j < 7; j++){
    float xx  = p[16 + j];
    float z   = __expf(-fabsf(xx));
    float sel = (xx >= 0.f) ? z : 1.f;
    dv[j + 1] = 0.001f + fmaxf(xx, 0.f) + __logf(1.f + z + sel);
  }

  const float xv  = x[(size_t)s * NDIM + xcol + d];
  const float xin = fminf(3.f, fmaxf(-3.f, xv));

  int b = 0;
  #pragma unroll
  for (int j = 1; j < 8; j++) b += (xin >= cumw[j]) ? 1 : 0;

  float in_cw = 0.f, in_w = 0.f, in_ch = 0.f, in_h = 0.f, in_d = 0.f, in_d1 = 0.f;
  #pragma unroll
  for (int j = 0; j < 8; j++){
    if (j == b){ in_cw = cumw[j]; in_w = wd[j]; in_ch = cumh[j];
                 in_h = hg[j];  in_d = dv[j]; in_d1 = dv[j + 1]; }
  }

  float rw    = frcp(in_w);
  float th    = (xin - in_cw) * rw;
  float tt    = th * (1.f - th);
  float delta = in_h * rw;
  float numer = in_h * (delta * th * th + in_d * tt);
  float denom = delta + (in_d + in_d1 - 2.f * delta) * tt;
  float rden  = frcp(denom);
  float outv  = in_ch + numer * rden;
  float omt   = 1.f - th;
  float dnum  = delta * delta * (in_d1 * th * th + 2.f * delta * tt + in_d * omt * omt);
  float lad   = __logf(dnum * rden * rden);

  bool inside = (xv >= -3.f) && (xv <= 3.f);
  outv = inside ? outv : xv;
  lad  = inside ? lad  : 0.f;

  out[(size_t)s * NDIM + xcol + d] = outv;

  float v = lad;
  #pragma unroll
  for (int mm = 1; mm < 32; mm <<= 1) v += __shfl_xor(v, mm, 64);
  if (d == 0){
    if (PHASE == 0) ldp[s] = v;
    else            ldout[s] = ldp[s] + v;
  }
}

extern "C" void kernel_launch(void* const* d_in, const int* in_sizes, int n_in,
                              void* d_out, int out_size, void* d_ws, size_t ws_size,
                              hipStream_t stream)
{
  const float* x    = (const float*)d_in[0];
  const float* f1w0 = (const float*)d_in[1];
  const float* f1b0 = (const float*)d_in[2];
  const float* f1w1 = (const float*)d_in[3];
  const float* f1b1 = (const float*)d_in[4];
  const float* f1w2 = (const float*)d_in[5];
  const float* f1b2 = (const float*)d_in[6];
  const float* f2w0 = (const float*)d_in[7];
  const float* f2b0 = (const float*)d_in[8];
  const float* f2w1 = (const float*)d_in[9];
  const float* f2b1 = (const float*)d_in[10];
  const float* f2w2 = (const float*)d_in[11];
  const float* f2b2 = (const float*)d_in[12];

  const int N = in_sizes[0] / NDIM;   // 65536
  float* out = (float*)d_out;
  float* ldout = out + (size_t)N * NDIM;

  u16* h1 = (u16*)d_ws;
  u16* h2 = h1 + (size_t)N * NHID;
  u16* pr = h2 + (size_t)N * NHID;
  float* ld1 = (float*)(pr + (size_t)N * NPAR);
  u16* wb  = (u16*)(ld1 + N);
  u16* w0t = wb;                       // 256 x 32
  u16* w1t = w0t + 256 * 32;           // 256 x 256
  u16* w2t = w1t + 256 * 256;          // 768 x 256 (rows 736.. zero)
  u16* xb  = pr;                       // alias (lifetimes disjoint)

  dim3 blk(256);
  dim3 g256(N / 128, 2);               // J=256
  dim3 g736(N / 128, 6);               // Jpad=768
  dim3 gw(1056);                       // 270336 weight elements
  dim3 gx(N * 8 / 256);
  dim3 gs(N / 8);

  // ---- coupling 1
  wconv3_k<<<gw, blk, 0, stream>>>(f1w0, f1w1, f1w2, w0t, w1t, w2t);
  xconv_k<<<gx, blk, 0, stream>>>(x, xb, 0);
  mfma_gemm<true ><<<g256, blk, 0, stream>>>(xb, w0t, f1b0, h1, 32,  256);
  mfma_gemm<true ><<<g256, blk, 0, stream>>>(h1, w1t, f1b1, h2, 256, 256);
  mfma_gemm<false><<<g736, blk, 0, stream>>>(h2, w2t, f1b2, pr, 256, 736);
  spline_k<0><<<gs, blk, 0, stream>>>(x, pr, out, ld1, ldout, NHALF);

  // ---- coupling 2
  wconv3_k<<<gw, blk, 0, stream>>>(f2w0, f2w1, f2w2, w0t, w1t, w2t);
  xconv_k<<<gx, blk, 0, stream>>>(out, xb, NHALF);
  mfma_gemm<true ><<<g256, blk, 0, stream>>>(xb, w0t, f2b0, h1, 32,  256);
  mfma_gemm<true ><<<g256, blk, 0, stream>>>(h1, w1t, f2b1, h2, 256, 256);
  mfma_gemm<false><<<g736, blk, 0, stream>>>(h2, w2t, f2b2, pr, 256, 736);
  spline_k<1><<<gs, blk, 0, stream>>>(x, pr, out, ld1, ldout, 0);
}

// Round 12
// 351.020 us; speedup vs baseline: 3.3619x; 1.0090x over previous
//
#include <hip/hip_runtime.h>

#define NHALF 32
#define NDIM  64
#define NHID  256
#define NPAR  736   // (3K-1)*HALF = 23*32

typedef unsigned short u16;
typedef unsigned int   u32;
typedef __attribute__((ext_vector_type(8))) short short8;   // 8 bf16 = 4 VGPR
typedef __attribute__((ext_vector_type(4))) float f32x4;

__device__ __forceinline__ float bf2f(u16 h){ return __uint_as_float(((u32)h) << 16); }
__device__ __forceinline__ u16 f2bf(float f){
  u32 u = __float_as_uint(f);
  u += 0x7FFFu + ((u >> 16) & 1u);   // round-to-nearest-even
  return (u16)(u >> 16);
}
__device__ __forceinline__ float frcp(float x){ return __builtin_amdgcn_rcpf(x); }
__device__ __forceinline__ float tanh_fast(float x){
  x = fminf(15.f, fmaxf(-15.f, x));
  float e = __expf(2.f * x);
  return 1.f - 2.f * frcp(e + 1.f);
}

__device__ __forceinline__ void gload16(const u16* g, u16* l){
  __builtin_amdgcn_global_load_lds(
      (const __attribute__((address_space(1))) unsigned int*)(g),
      (__attribute__((address_space(3))) unsigned int*)(l), 16, 0, 0);
}

// ---------------- MFMA GEMM: C[M x Jreal](bf16) = act(A[M x K](bf16) @ Wt^T + bias)
// R9: 128x256 tile (was 128x128), 4 waves (2x2), per-wave 64x128 = 4x8 frags.
// Rationale (R8 counters): 128x128 was LDS-read-pipe co-limited (12 waves x 8
// ds_read x 12cyc > MFMA cycles); 32 MFMA per 12 ds_read cuts LDS/FLOP 25%,
// halves block count (half the epilogues, A refetched 3x not 6x).
// Registers: acc 128 AGPR + ~80 VGPR -> 2 waves/SIMD (launch_bounds(256,2)).
// LDS: 2 x (A 8KB + B 16KB) = 48KB -> 2 blocks/CU.
// Grid 1-D, y-fastest decode: the NJT col-tiles sharing an A-row-block are
// dispatch-adjacent -> A re-reads hit L2/L3.
template<bool TANH>
__global__ __launch_bounds__(256, 2)
void mfma_gemm(const u16* __restrict__ A, const u16* __restrict__ Wt,
               const float* __restrict__ bias, u16* __restrict__ C,
               int K, int Jreal, int njt)
{
  __shared__ __align__(16) u16 sm[2 * 12288];   // 49152 B
  const int t    = threadIdx.x;
  const int lane = t & 63, w = t >> 6;
  const int wr   = w >> 1, wc = w & 1;
  const int lm   = lane & 15, lk = lane >> 4;
  const int bid  = blockIdx.x;
  const int jt   = bid % njt;            // y-fastest: A-sharers adjacent
  const int row0 = (bid / njt) * 128;
  const int jb   = jt * 256;

  f32x4 acc[4][8];
  #pragma unroll
  for (int i = 0; i < 4; i++)
    #pragma unroll
    for (int j = 0; j < 8; j++) acc[i][j] = (f32x4){0.f, 0.f, 0.f, 0.f};

  const int nk = K >> 5;

  auto stage = [&](int buf, int ks){
    const int kk = ks << 5;
    u16* base = sm + buf * 12288;
    #pragma unroll
    for (int h = 0; h < 2; h++){          // A: 8 subtiles of 16 rows
      int s = w + h * 4;
      gload16(A + (size_t)(row0 + s * 16 + lm) * K + kk + lk * 8, base + s * 512);
    }
    #pragma unroll
    for (int h = 0; h < 4; h++){          // B: 16 subtiles of 16 cols
      int s = w + h * 4;
      gload16(Wt + (size_t)(jb + s * 16 + lm) * K + kk + lk * 8, base + 4096 + s * 512);
    }
  };

  auto compute = [&](int buf){
    const u16* base = sm + buf * 12288;
    short8 a[4], b[8];
    #pragma unroll
    for (int i = 0; i < 4; i++)
      a[i] = *(const short8*)(base + (wr * 4 + i) * 512 + lane * 8);
    #pragma unroll
    for (int j = 0; j < 8; j++)
      b[j] = *(const short8*)(base + 4096 + (wc * 8 + j) * 512 + lane * 8);
    #pragma unroll
    for (int i = 0; i < 4; i++)
      #pragma unroll
      for (int j = 0; j < 8; j++)
        acc[i][j] = __builtin_amdgcn_mfma_f32_16x16x32_bf16(a[i], b[j], acc[i][j], 0, 0, 0);
  };

  stage(0, 0);
  __syncthreads();
  for (int ks = 0; ks < nk; ++ks){
    if (ks + 1 < nk) stage((ks + 1) & 1, ks + 1);
    compute(ks & 1);
    __syncthreads();   // final barrier also protects epilogue overlay of staging LDS
  }

  // ---- epilogue: two 32-row halves through wave-private [32][132] LDS, then
  // coalesced 256B-contiguous dwordx4 row stores.
  const int rbase = row0 + wr * 64;
  const int cbase = jb + wc * 128;
  u16* ep = sm + w * 4224;                  // 8448 B per wave
  float bs[8];
  #pragma unroll
  for (int j = 0; j < 8; j++){
    int col = cbase + j * 16 + lm;
    bs[j] = (col < Jreal) ? bias[col] : 0.f;
  }
  const int lr4 = lane >> 4, ch = lane & 15;
  #pragma unroll
  for (int h = 0; h < 2; h++){
    #pragma unroll
    for (int ii = 0; ii < 2; ii++){
      int i = h * 2 + ii;
      #pragma unroll
      for (int j = 0; j < 8; j++){
        #pragma unroll
        for (int r = 0; r < 4; r++){
          float v = acc[i][j][r] + bs[j];
          if (TANH) v = tanh_fast(v);
          ep[(ii * 16 + lk * 4 + r) * 132 + j * 16 + lm] = f2bf(v);
        }
      }
    }
    #pragma unroll
    for (int pass = 0; pass < 8; pass++){
      int lr = pass * 4 + lr4;
      uint4 v = *(const uint4*)(ep + lr * 132 + ch * 8);
      int col0 = cbase + ch * 8;
      if (col0 + 7 < Jreal)
        *(uint4*)(C + (size_t)(rbase + h * 32 + lr) * Jreal + col0) = v;
    }
  }
}

// x-slice fp32 -> dense bf16 [N][32]
__global__ __launch_bounds__(256)
void xconv_k(const float* __restrict__ in, u16* __restrict__ out, int col0){
  int tid = blockIdx.x * 256 + threadIdx.x;       // N*8 threads
  int row = tid >> 3, c4 = (tid & 7) << 2;
  float4 v = *(const float4*)(in + (size_t)row * NDIM + col0 + c4);
  ushort4 o; o.x = f2bf(v.x); o.y = f2bf(v.y); o.z = f2bf(v.z); o.w = f2bf(v.w);
  *(ushort4*)(out + (size_t)row * NHALF + c4) = o;
}

// All three weight conversions in one launch.
__global__ __launch_bounds__(256)
void wconv3_k(const float* __restrict__ W0, const float* __restrict__ W1,
              const float* __restrict__ W2,
              u16* __restrict__ w0t, u16* __restrict__ w1t, u16* __restrict__ w2t){
  int tid = blockIdx.x * 256 + threadIdx.x;
  if (tid < 8192){
    int n = tid >> 5, k = tid & 31;
    w0t[tid] = f2bf(W0[(size_t)k * 256 + n]);
  } else if (tid < 73728){
    int id = tid - 8192; int n = id >> 8, k = id & 255;
    w1t[id] = f2bf(W1[(size_t)k * 256 + n]);
  } else if (tid < 270336){
    int id = tid - 73728; int n = id >> 8, k = id & 255;
    w2t[id] = (n < 736) ? f2bf(W2[(size_t)k * 736 + n]) : (u16)0;
  }
}

// ---------------- spline (byte-identical to passing R5-R8 version) ----------------
template<int PHASE>
__global__ __launch_bounds__(256)
void spline_k(const float* __restrict__ x,
              const u16* __restrict__ params,
              float* __restrict__ out,
              float* __restrict__ ldp,
              float* __restrict__ ldout,
              int xcol)
{
  __shared__ u16 pb[8 * NPAR];
  const int t = threadIdx.x;
  const int s0 = blockIdx.x * 8;

  {
    const uint4* src = (const uint4*)(params + (size_t)s0 * NPAR);
    uint4* dst = (uint4*)pb;
    dst[t]       = src[t];
    dst[256 + t] = src[256 + t];
    if (t < 224) dst[512 + t] = src[512 + t];
  }
  __syncthreads();

  const int si = t >> 5, d = t & 31;
  const int s = s0 + si;
  const u16* pp = pb + si * NPAR + d * 23;
  float p[23];
  #pragma unroll
  for (int e = 0; e < 23; e++) p[e] = bf2f(pp[e]);

  float W6[8], H6[8];
  {
    float m = p[0];
    #pragma unroll
    for (int i = 1; i < 8; i++) m = fmaxf(m, p[i]);
    float sm = 0.f;
    #pragma unroll
    for (int i = 0; i < 8; i++){ W6[i] = __expf(p[i] - m); sm += W6[i]; }
    float r = 6.f * frcp(sm);
    #pragma unroll
    for (int i = 0; i < 8; i++) W6[i] *= r;
  }
  {
    float m = p[8];
    #pragma unroll
    for (int i = 1; i < 8; i++) m = fmaxf(m, p[8 + i]);
    float sm = 0.f;
    #pragma unroll
    for (int i = 0; i < 8; i++){ H6[i] = __expf(p[8 + i] - m); sm += H6[i]; }
    float r = 6.f * frcp(sm);
    #pragma unroll
    for (int i = 0; i < 8; i++) H6[i] *= r;
  }

  float wd[8], cumw[9];
  {
    float sm = 0.f;
    #pragma unroll
    for (int i = 0; i < 8; i++){ wd[i] = __expf(W6[i]); sm += wd[i]; }
    float r = 0.992f * frcp(sm);
    #pragma unroll
    for (int i = 0; i < 8; i++) wd[i] = 0.001f + wd[i] * r;
  }
  cumw[0] = -3.f;
  { float run = 0.f;
    #pragma unroll
    for (int i = 0; i < 8; i++){ run += wd[i]; cumw[i + 1] = 6.f * run - 3.f; } }
  cumw[8] = 3.f;
  #pragma unroll
  for (int i = 0; i < 8; i++) wd[i] = cumw[i + 1] - cumw[i];

  float hg[8], cumh[9];
  {
    float sm = 0.f;
    #pragma unroll
    for (int i = 0; i < 8; i++){ hg[i] = __expf(H6[i]); sm += hg[i]; }
    float r = 0.992f * frcp(sm);
    #pragma unroll
    for (int i = 0; i < 8; i++) hg[i] = 0.001f + hg[i] * r;
  }
  cumh[0] = -3.f;
  { float run = 0.f;
    #pragma unroll
    for (int i = 0; i < 8; i++){ run += hg[i]; cumh[i + 1] = 6.f * run - 3.f; } }
  cumh[8] = 3.f;
  #pragma unroll
  for (int i = 0; i < 8; i++) hg[i] = cumh[i + 1] - cumh[i];

  float dv[9];
  dv[0] = 1.f; dv[8] = 1.f;
  #pragma unroll
  for (int j = 0; j < 7; j++){
    float xx  = p[16 + j];
    float z   = __expf(-fabsf(xx));
    float sel = (xx >= 0.f) ? z : 1.f;
    dv[j + 1] = 0.001f + fmaxf(xx, 0.f) + __logf(1.f + z + sel);
  }

  const float xv  = x[(size_t)s * NDIM + xcol + d];
  const float xin = fminf(3.f, fmaxf(-3.f, xv));

  int b = 0;
  #pragma unroll
  for (int j = 1; j < 8; j++) b += (xin >= cumw[j]) ? 1 : 0;

  float in_cw = 0.f, in_w = 0.f, in_ch = 0.f, in_h = 0.f, in_d = 0.f, in_d1 = 0.f;
  #pragma unroll
  for (int j = 0; j < 8; j++){
    if (j == b){ in_cw = cumw[j]; in_w = wd[j]; in_ch = cumh[j];
                 in_h = hg[j];  in_d = dv[j]; in_d1 = dv[j + 1]; }
  }

  float rw    = frcp(in_w);
  float th    = (xin - in_cw) * rw;
  float tt    = th * (1.f - th);
  float delta = in_h * rw;
  float numer = in_h * (delta * th * th + in_d * tt);
  float denom = delta + (in_d + in_d1 - 2.f * delta) * tt;
  float rden  = frcp(denom);
  float outv  = in_ch + numer * rden;
  float omt   = 1.f - th;
  float dnum  = delta * delta * (in_d1 * th * th + 2.f * delta * tt + in_d * omt * omt);
  float lad   = __logf(dnum * rden * rden);

  bool inside = (xv >= -3.f) && (xv <= 3.f);
  outv = inside ? outv : xv;
  lad  = inside ? lad  : 0.f;

  out[(size_t)s * NDIM + xcol + d] = outv;

  float v = lad;
  #pragma unroll
  for (int mm = 1; mm < 32; mm <<= 1) v += __shfl_xor(v, mm, 64);
  if (d == 0){
    if (PHASE == 0) ldp[s] = v;
    else            ldout[s] = ldp[s] + v;
  }
}

extern "C" void kernel_launch(void* const* d_in, const int* in_sizes, int n_in,
                              void* d_out, int out_size, void* d_ws, size_t ws_size,
                              hipStream_t stream)
{
  const float* x    = (const float*)d_in[0];
  const float* f1w0 = (const float*)d_in[1];
  const float* f1b0 = (const float*)d_in[2];
  const float* f1w1 = (const float*)d_in[3];
  const float* f1b1 = (const float*)d_in[4];
  const float* f1w2 = (const float*)d_in[5];
  const float* f1b2 = (const float*)d_in[6];
  const float* f2w0 = (const float*)d_in[7];
  const float* f2b0 = (const float*)d_in[8];
  const float* f2w1 = (const float*)d_in[9];
  const float* f2b1 = (const float*)d_in[10];
  const float* f2w2 = (const float*)d_in[11];
  const float* f2b2 = (const float*)d_in[12];

  const int N = in_sizes[0] / NDIM;   // 65536
  float* out = (float*)d_out;
  float* ldout = out + (size_t)N * NDIM;

  u16* h1 = (u16*)d_ws;
  u16* h2 = h1 + (size_t)N * NHID;
  u16* pr = h2 + (size_t)N * NHID;
  float* ld1 = (float*)(pr + (size_t)N * NPAR);
  u16* wb  = (u16*)(ld1 + N);
  u16* w0t = wb;                       // 256 x 32
  u16* w1t = w0t + 256 * 32;           // 256 x 256
  u16* w2t = w1t + 256 * 256;          // 768 x 256 (rows 736.. zero)
  u16* xb  = pr;                       // alias (lifetimes disjoint)

  dim3 blk(256);
  dim3 g256(N / 128);                  // J=256: 1 col-tile, 512 blocks
  dim3 g736(N / 128 * 3);              // Jpad=768: 3 col-tiles, 1536 blocks
  dim3 gw(1056);                       // 270336 weight elements
  dim3 gx(N * 8 / 256);
  dim3 gs(N / 8);

  // ---- coupling 1
  wconv3_k<<<gw, blk, 0, stream>>>(f1w0, f1w1, f1w2, w0t, w1t, w2t);
  xconv_k<<<gx, blk, 0, stream>>>(x, xb, 0);
  mfma_gemm<true ><<<g256, blk, 0, stream>>>(xb, w0t, f1b0, h1, 32,  256, 1);
  mfma_gemm<true ><<<g256, blk, 0, stream>>>(h1, w1t, f1b1, h2, 256, 256, 1);
  mfma_gemm<false><<<g736, blk, 0, stream>>>(h2, w2t, f1b2, pr, 256, 736, 3);
  spline_k<0><<<gs, blk, 0, stream>>>(x, pr, out, ld1, ldout, NHALF);

  // ---- coupling 2
  wconv3_k<<<gw, blk, 0, stream>>>(f2w0, f2w1, f2w2, w0t, w1t, w2t);
  xconv_k<<<gx, blk, 0, stream>>>(out, xb, NHALF);
  mfma_gemm<true ><<<g256, blk, 0, stream>>>(xb, w0t, f2b0, h1, 32,  256, 1);
  mfma_gemm<true ><<<g256, blk, 0, stream>>>(h1, w1t, f2b1, h2, 256, 256, 1);
  mfma_gemm<false><<<g736, blk, 0, stream>>>(h2, w2t, f2b2, pr, 256, 736, 3);
  spline_k<1><<<gs, blk, 0, stream>>>(x, pr, out, ld1, ldout, 0);
}

// Round 14
// 287.423 us; speedup vs baseline: 4.1057x; 1.2213x over previous
//
#include <hip/hip_runtime.h>

#define NHALF 32
#define NDIM  64
#define NHID  256
#define NPAR  736   // (3K-1)*HALF = 23*32

typedef unsigned short u16;
typedef unsigned int   u32;
typedef __attribute__((ext_vector_type(8))) short short8;   // 8 bf16 = 4 VGPR
typedef __attribute__((ext_vector_type(4))) float f32x4;

__device__ __forceinline__ float bf2f(u16 h){ return __uint_as_float(((u32)h) << 16); }
__device__ __forceinline__ u16 f2bf(float f){
  u32 u = __float_as_uint(f);
  u += 0x7FFFu + ((u >> 16) & 1u);   // round-to-nearest-even
  return (u16)(u >> 16);
}
__device__ __forceinline__ float frcp(float x){ return __builtin_amdgcn_rcpf(x); }
__device__ __forceinline__ float tanh_fast(float x){
  x = fminf(15.f, fmaxf(-15.f, x));
  float e = __expf(2.f * x);
  return 1.f - 2.f * frcp(e + 1.f);
}

// h-buffer addressing: row-major stride 264 u16 (528B, 16B-aligned rows),
// col XOR-swizzled by ((row>>2)&3)<<3 (flips u16-index bits 3,4 -> keeps
// 8-element runs contiguous & 16B-aligned; bijective within col<256).
// Write shape (row=..+lk*4+r, col=..+lm): banks = all 32, 2-way = free.
// Read shape (row=..+lm, col=ks*32+lk*8): ~even spread, <=2-way.
__device__ __forceinline__ int hoff(int row, int col){
  return row * 264 + (col ^ (((row >> 2) & 3) << 3));
}

// ---------------- Fused MLP: pr[N x 736] = (tanh(tanh(x@W0+b0)@W1+b1))@W2+b2
// One block = 128 rows, 4 waves; h1/h2 share one 67.6KB LDS buffer
// (h2 overwrites h1 after a barrier). B-fragments read per-lane from global
// (weights L2-resident); A-frags for L0 read directly from fp32 X.
// No K-loop vmcnt drains; the only barriers are the 3 layer boundaries.
template<int XCOL>
__global__ __launch_bounds__(256, 2)
void mlp_fused(const float* __restrict__ X,   // [N][64] fp32
               const u16* __restrict__ w0t,   // [256][32]  n-major
               const u16* __restrict__ w1t,   // [256][256] n-major
               const u16* __restrict__ w2t,   // [768][256] n-major (rows>=736 zero)
               const float* __restrict__ b0, const float* __restrict__ b1,
               const float* __restrict__ b2,
               u16* __restrict__ pr)          // [N][736]
{
  __shared__ __align__(16) u16 hb[128 * 264];  // 67584 B
  const int t = threadIdx.x, lane = t & 63, w = t >> 6;
  const int lm = lane & 15, lk = lane >> 4;
  const int row0 = blockIdx.x * 128;
  const int cb = w * 64;                       // wave's col slice for L0/L1

  f32x4 acc[8][4];
  const f32x4 zf = (f32x4){0.f, 0.f, 0.f, 0.f};

  // ---------- L0: h1 = tanh(x @ W0t^T + b0), K=32 (one MFMA per frag pair)
  {
    short8 a[8];
    #pragma unroll
    for (int mf = 0; mf < 8; mf++){
      const float* xp = X + (size_t)(row0 + mf * 16 + lm) * NDIM + XCOL + lk * 8;
      float4 v0 = *(const float4*)xp;
      float4 v1 = *(const float4*)(xp + 4);
      u16 tmp[8];
      tmp[0] = f2bf(v0.x); tmp[1] = f2bf(v0.y); tmp[2] = f2bf(v0.z); tmp[3] = f2bf(v0.w);
      tmp[4] = f2bf(v1.x); tmp[5] = f2bf(v1.y); tmp[6] = f2bf(v1.z); tmp[7] = f2bf(v1.w);
      a[mf] = *(const short8*)tmp;
    }
    #pragma unroll
    for (int nf = 0; nf < 4; nf++){
      short8 b = *(const short8*)(w0t + (size_t)(cb + nf * 16 + lm) * 32 + lk * 8);
      #pragma unroll
      for (int mf = 0; mf < 8; mf++)
        acc[mf][nf] = __builtin_amdgcn_mfma_f32_16x16x32_bf16(a[mf], b, zf, 0, 0, 0);
    }
    #pragma unroll
    for (int nf = 0; nf < 4; nf++){
      int col = cb + nf * 16 + lm;
      float bs = b0[col];
      #pragma unroll
      for (int mf = 0; mf < 8; mf++)
        #pragma unroll
        for (int r = 0; r < 4; r++)
          hb[hoff(mf * 16 + lk * 4 + r, col)] = f2bf(tanh_fast(acc[mf][nf][r] + bs));
    }
  }
  __syncthreads();

  // ---------- L1: h2 = tanh(h1 @ W1t^T + b1), K=256
  #pragma unroll
  for (int mf = 0; mf < 8; mf++)
    #pragma unroll
    for (int nf = 0; nf < 4; nf++) acc[mf][nf] = zf;
  for (int ks = 0; ks < 8; ks++){
    short8 av[8], bv[4];
    #pragma unroll
    for (int mf = 0; mf < 8; mf++)
      av[mf] = *(const short8*)(hb + hoff(mf * 16 + lm, ks * 32 + lk * 8));
    #pragma unroll
    for (int nf = 0; nf < 4; nf++)
      bv[nf] = *(const short8*)(w1t + (size_t)(cb + nf * 16 + lm) * 256 + ks * 32 + lk * 8);
    #pragma unroll
    for (int mf = 0; mf < 8; mf++)
      #pragma unroll
      for (int nf = 0; nf < 4; nf++)
        acc[mf][nf] = __builtin_amdgcn_mfma_f32_16x16x32_bf16(av[mf], bv[nf], acc[mf][nf], 0, 0, 0);
  }
  __syncthreads();                 // all h1 reads complete before overwrite
  {
    #pragma unroll
    for (int nf = 0; nf < 4; nf++){
      int col = cb + nf * 16 + lm;
      float bs = b1[col];
      #pragma unroll
      for (int mf = 0; mf < 8; mf++)
        #pragma unroll
        for (int r = 0; r < 4; r++)
          hb[hoff(mf * 16 + lk * 4 + r, col)] = f2bf(tanh_fast(acc[mf][nf][r] + bs));
    }
  }
  __syncthreads();

  // ---------- L2: pr = h2 @ W2t^T + b2, K=256, 768 cols in 3 passes/wave
  #pragma unroll 1
  for (int p = 0; p < 3; p++){
    const int cb2 = p * 256 + w * 64;
    #pragma unroll
    for (int mf = 0; mf < 8; mf++)
      #pragma unroll
      for (int nf = 0; nf < 4; nf++) acc[mf][nf] = zf;
    for (int ks = 0; ks < 8; ks++){
      short8 av[8], bv[4];
      #pragma unroll
      for (int mf = 0; mf < 8; mf++)
        av[mf] = *(const short8*)(hb + hoff(mf * 16 + lm, ks * 32 + lk * 8));
      #pragma unroll
      for (int nf = 0; nf < 4; nf++)
        bv[nf] = *(const short8*)(w2t + (size_t)(cb2 + nf * 16 + lm) * 256 + ks * 32 + lk * 8);
      #pragma unroll
      for (int mf = 0; mf < 8; mf++)
        #pragma unroll
        for (int nf = 0; nf < 4; nf++)
          acc[mf][nf] = __builtin_amdgcn_mfma_f32_16x16x32_bf16(av[mf], bv[nf], acc[mf][nf], 0, 0, 0);
    }
    #pragma unroll
    for (int nf = 0; nf < 4; nf++){
      int col = cb2 + nf * 16 + lm;
      if (col < NPAR){
        float bs = b2[col];
        #pragma unroll
        for (int mf = 0; mf < 8; mf++)
          #pragma unroll
          for (int r = 0; r < 4; r++)
            pr[(size_t)(row0 + mf * 16 + lk * 4 + r) * NPAR + col] = f2bf(acc[mf][nf][r] + bs);
      }
    }
  }
}

// All three weight conversions in one launch (unchanged from R7/R12).
__global__ __launch_bounds__(256)
void wconv3_k(const float* __restrict__ W0, const float* __restrict__ W1,
              const float* __restrict__ W2,
              u16* __restrict__ w0t, u16* __restrict__ w1t, u16* __restrict__ w2t){
  int tid = blockIdx.x * 256 + threadIdx.x;
  if (tid < 8192){
    int n = tid >> 5, k = tid & 31;
    w0t[tid] = f2bf(W0[(size_t)k * 256 + n]);
  } else if (tid < 73728){
    int id = tid - 8192; int n = id >> 8, k = id & 255;
    w1t[id] = f2bf(W1[(size_t)k * 256 + n]);
  } else if (tid < 270336){
    int id = tid - 73728; int n = id >> 8, k = id & 255;
    w2t[id] = (n < 736) ? f2bf(W2[(size_t)k * 736 + n]) : (u16)0;
  }
}

// ---------------- spline (byte-identical to passing R5-R12 version) ----------------
template<int PHASE>
__global__ __launch_bounds__(256)
void spline_k(const float* __restrict__ x,
              const u16* __restrict__ params,
              float* __restrict__ out,
              float* __restrict__ ldp,
              float* __restrict__ ldout,
              int xcol)
{
  __shared__ u16 pb[8 * NPAR];
  const int t = threadIdx.x;
  const int s0 = blockIdx.x * 8;

  {
    const uint4* src = (const uint4*)(params + (size_t)s0 * NPAR);
    uint4* dst = (uint4*)pb;
    dst[t]       = src[t];
    dst[256 + t] = src[256 + t];
    if (t < 224) dst[512 + t] = src[512 + t];
  }
  __syncthreads();

  const int si = t >> 5, d = t & 31;
  const int s = s0 + si;
  const u16* pp = pb + si * NPAR + d * 23;
  float p[23];
  #pragma unroll
  for (int e = 0; e < 23; e++) p[e] = bf2f(pp[e]);

  float W6[8], H6[8];
  {
    float m = p[0];
    #pragma unroll
    for (int i = 1; i < 8; i++) m = fmaxf(m, p[i]);
    float sm = 0.f;
    #pragma unroll
    for (int i = 0; i < 8; i++){ W6[i] = __expf(p[i] - m); sm += W6[i]; }
    float r = 6.f * frcp(sm);
    #pragma unroll
    for (int i = 0; i < 8; i++) W6[i] *= r;
  }
  {
    float m = p[8];
    #pragma unroll
    for (int i = 1; i < 8; i++) m = fmaxf(m, p[8 + i]);
    float sm = 0.f;
    #pragma unroll
    for (int i = 0; i < 8; i++){ H6[i] = __expf(p[8 + i] - m); sm += H6[i]; }
    float r = 6.f * frcp(sm);
    #pragma unroll
    for (int i = 0; i < 8; i++) H6[i] *= r;
  }

  float wd[8], cumw[9];
  {
    float sm = 0.f;
    #pragma unroll
    for (int i = 0; i < 8; i++){ wd[i] = __expf(W6[i]); sm += wd[i]; }
    float r = 0.992f * frcp(sm);
    #pragma unroll
    for (int i = 0; i < 8; i++) wd[i] = 0.001f + wd[i] * r;
  }
  cumw[0] = -3.f;
  { float run = 0.f;
    #pragma unroll
    for (int i = 0; i < 8; i++){ run += wd[i]; cumw[i + 1] = 6.f * run - 3.f; } }
  cumw[8] = 3.f;
  #pragma unroll
  for (int i = 0; i < 8; i++) wd[i] = cumw[i + 1] - cumw[i];

  float hg[8], cumh[9];
  {
    float sm = 0.f;
    #pragma unroll
    for (int i = 0; i < 8; i++){ hg[i] = __expf(H6[i]); sm += hg[i]; }
    float r = 0.992f * frcp(sm);
    #pragma unroll
    for (int i = 0; i < 8; i++) hg[i] = 0.001f + hg[i] * r;
  }
  cumh[0] = -3.f;
  { float run = 0.f;
    #pragma unroll
    for (int i = 0; i < 8; i++){ run += hg[i]; cumh[i + 1] = 6.f * run - 3.f; } }
  cumh[8] = 3.f;
  #pragma unroll
  for (int i = 0; i < 8; i++) hg[i] = cumh[i + 1] - cumh[i];

  float dv[9];
  dv[0] = 1.f; dv[8] = 1.f;
  #pragma unroll
  for (int j = 0; j < 7; j++){
    float xx  = p[16 + j];
    float z   = __expf(-fabsf(xx));
    float sel = (xx >= 0.f) ? z : 1.f;
    dv[j + 1] = 0.001f + fmaxf(xx, 0.f) + __logf(1.f + z + sel);
  }

  const float xv  = x[(size_t)s * NDIM + xcol + d];
  const float xin = fminf(3.f, fmaxf(-3.f, xv));

  int b = 0;
  #pragma unroll
  for (int j = 1; j < 8; j++) b += (xin >= cumw[j]) ? 1 : 0;

  float in_cw = 0.f, in_w = 0.f, in_ch = 0.f, in_h = 0.f, in_d = 0.f, in_d1 = 0.f;
  #pragma unroll
  for (int j = 0; j < 8; j++){
    if (j == b){ in_cw = cumw[j]; in_w = wd[j]; in_ch = cumh[j];
                 in_h = hg[j];  in_d = dv[j]; in_d1 = dv[j + 1]; }
  }

  float rw    = frcp(in_w);
  float th    = (xin - in_cw) * rw;
  float tt    = th * (1.f - th);
  float delta = in_h * rw;
  float numer = in_h * (delta * th * th + in_d * tt);
  float denom = delta + (in_d + in_d1 - 2.f * delta) * tt;
  float rden  = frcp(denom);
  float outv  = in_ch + numer * rden;
  float omt   = 1.f - th;
  float dnum  = delta * delta * (in_d1 * th * th + 2.f * delta * tt + in_d * omt * omt);
  float lad   = __logf(dnum * rden * rden);

  bool inside = (xv >= -3.f) && (xv <= 3.f);
  outv = inside ? outv : xv;
  lad  = inside ? lad  : 0.f;

  out[(size_t)s * NDIM + xcol + d] = outv;

  float v = lad;
  #pragma unroll
  for (int mm = 1; mm < 32; mm <<= 1) v += __shfl_xor(v, mm, 64);
  if (d == 0){
    if (PHASE == 0) ldp[s] = v;
    else            ldout[s] = ldp[s] + v;
  }
}

extern "C" void kernel_launch(void* const* d_in, const int* in_sizes, int n_in,
                              void* d_out, int out_size, void* d_ws, size_t ws_size,
                              hipStream_t stream)
{
  const float* x    = (const float*)d_in[0];
  const float* f1w0 = (const float*)d_in[1];
  const float* f1b0 = (const float*)d_in[2];
  const float* f1w1 = (const float*)d_in[3];
  const float* f1b1 = (const float*)d_in[4];
  const float* f1w2 = (const float*)d_in[5];
  const float* f1b2 = (const float*)d_in[6];
  const float* f2w0 = (const float*)d_in[7];
  const float* f2b0 = (const float*)d_in[8];
  const float* f2w1 = (const float*)d_in[9];
  const float* f2b1 = (const float*)d_in[10];
  const float* f2w2 = (const float*)d_in[11];
  const float* f2b2 = (const float*)d_in[12];

  const int N = in_sizes[0] / NDIM;   // 65536
  float* out = (float*)d_out;
  float* ldout = out + (size_t)N * NDIM;

  // ws: pr (N*736 bf16) | ld1 (N f32) | w0t | w1t | w2t
  u16* pr = (u16*)d_ws;
  float* ld1 = (float*)(pr + (size_t)N * NPAR);
  u16* w0t = (u16*)(ld1 + N);          // 256 x 32
  u16* w1t = w0t + 256 * 32;           // 256 x 256
  u16* w2t = w1t + 256 * 256;          // 768 x 256 (rows 736.. zero)

  dim3 blk(256);
  dim3 gm(N / 128);                    // 512 blocks
  dim3 gw(1056);
  dim3 gs(N / 8);

  // ---- coupling 1: f1(x[:, :32]) -> transform upper
  wconv3_k<<<gw, blk, 0, stream>>>(f1w0, f1w1, f1w2, w0t, w1t, w2t);
  mlp_fused<0><<<gm, blk, 0, stream>>>(x, w0t, w1t, w2t, f1b0, f1b1, f1b2, pr);
  spline_k<0><<<gs, blk, 0, stream>>>(x, pr, out, ld1, ldout, NHALF);

  // ---- coupling 2: f2(out[:, 32:]) -> transform lower
  wconv3_k<<<gw, blk, 0, stream>>>(f2w0, f2w1, f2w2, w0t, w1t, w2t);
  mlp_fused<NHALF><<<gm, blk, 0, stream>>>(out, w0t, w1t, w2t, f2b0, f2b1, f2b2, pr);
  spline_k<1><<<gs, blk, 0, stream>>>(x, pr, out, ld1, ldout, 0);
}